// Round 1
// baseline (2459.877 us; speedup 1.0000x reference)
//
#include <hip/hip_runtime.h>
#include <math.h>

#define EPSV 1e-5f

// ---------------- BN over tokens (B,C,N), float4 ----------------
__global__ __launch_bounds__(256) void bn_affine_kernel(
    const float4* __restrict__ x, float4* __restrict__ y,
    const float* __restrict__ g, const float* __restrict__ be,
    const float* __restrict__ mu, const float* __restrict__ va)
{
    int i = blockIdx.x * 256 + threadIdx.x;      // over B*C*N/4
    int c = (i >> 11) & 255;                      // (i*4)/8192 % 256
    float s = g[c] * rsqrtf(va[c] + EPSV);
    float t = be[c] - mu[c] * s;
    float4 v = x[i];
    v.x = v.x * s + t; v.y = v.y * s + t; v.z = v.z * s + t; v.w = v.w * s + t;
    y[i] = v;
}

// ---------------- flatten einsum: out[b,c,m] = sum_n fm[b,m,n]*rbn[b,c,n] ----------------
// SGEMM: A=(256x8192) row-major, B=(4096x8192) row-major (B^T layout), C=(256x4096)
// BM=64 (c), BN=128 (m), BK=16, 512 threads, 4x4 per thread.
__global__ __launch_bounds__(512) void flatten_gemm(
    const float* __restrict__ A, const float* __restrict__ Bm, float* __restrict__ Cc)
{
    int b = blockIdx.z;
    int c0 = blockIdx.y * 64, m0 = blockIdx.x * 128;
    const float* Ab = A + b * 2097152;            // 256*8192
    const float* Bb = Bm + b * 33554432;          // 4096*8192
    __shared__ float As[16][68];
    __shared__ float Bs[16][132];
    int t = threadIdx.x;
    int tx = t & 31, ty = t >> 5;
    float acc[4][4] = {};
    for (int k0 = 0; k0 < 8192; k0 += 16) {
        if (t < 256) {
            int row = t >> 2, k4 = (t & 3) << 2;
            float4 v = *(const float4*)(Ab + (c0 + row) * 8192 + k0 + k4);
            As[k4 + 0][row] = v.x; As[k4 + 1][row] = v.y;
            As[k4 + 2][row] = v.z; As[k4 + 3][row] = v.w;
        }
        {
            int row = t >> 2, k4 = (t & 3) << 2;
            float4 v = *(const float4*)(Bb + (m0 + row) * 8192 + k0 + k4);
            Bs[k4 + 0][row] = v.x; Bs[k4 + 1][row] = v.y;
            Bs[k4 + 2][row] = v.z; Bs[k4 + 3][row] = v.w;
        }
        __syncthreads();
        #pragma unroll
        for (int kk = 0; kk < 16; kk++) {
            float4 a = *(const float4*)&As[kk][ty << 2];
            float4 bb = *(const float4*)&Bs[kk][tx << 2];
            float av[4] = {a.x, a.y, a.z, a.w};
            float bv[4] = {bb.x, bb.y, bb.z, bb.w};
            #pragma unroll
            for (int i = 0; i < 4; i++)
                #pragma unroll
                for (int j = 0; j < 4; j++)
                    acc[i][j] += av[i] * bv[j];
        }
        __syncthreads();
    }
    #pragma unroll
    for (int i = 0; i < 4; i++) {
        float4 v = {acc[i][0], acc[i][1], acc[i][2], acc[i][3]};
        *(float4*)(Cc + (b * 256 + c0 + (ty << 2) + i) * 4096 + m0 + (tx << 2)) = v;
    }
}

// ---------------- generic 1x1 conv: out[b,o,p] = act(sum_c w[o,c]x[b,c,p] + bias[o]) ----------------
// grid (P/64, Cout/64, B), 256 threads. Cin % 64 == 0.
__global__ __launch_bounds__(256) void conv1x1_kernel(
    const float* __restrict__ x, const float* __restrict__ w,
    const float* __restrict__ bias, float* __restrict__ out,
    int Cin, int Cout, int P, int act)
{
    __shared__ float xsm[64 * 64];
    __shared__ float wsm[64 * 64];
    int t = threadIdx.x;
    int b = blockIdx.z;
    int p0 = blockIdx.x * 64, o0 = blockIdx.y * 64;
    int pl = t & 63, og = t >> 6;
    float acc[16] = {};
    for (int cc = 0; cc < Cin; cc += 64) {
        __syncthreads();
        #pragma unroll
        for (int u = 0; u < 16; u++) {
            int idx = t + u * 256;
            int cl = idx >> 6, q = idx & 63;
            xsm[idx] = x[(b * Cin + cc + cl) * P + p0 + q];   // xsm[cl*64+q]
            wsm[idx] = w[(o0 + cl) * Cin + cc + q];           // wsm[ol*64+cl]
        }
        __syncthreads();
        #pragma unroll 8
        for (int c = 0; c < 64; c++) {
            float xv = xsm[c * 64 + pl];
            #pragma unroll
            for (int oo = 0; oo < 16; oo++)
                acc[oo] += wsm[(og + (oo << 2)) * 64 + c] * xv;
        }
    }
    #pragma unroll
    for (int oo = 0; oo < 16; oo++) {
        int o = o0 + og + (oo << 2);
        float v = acc[oo] + bias[o];
        if (act == 1) v = fmaxf(v, 0.f);
        else if (act == 2) v = 0.5f * v * (1.f + erff(v * 0.70710678118f));
        out[(b * Cout + o) * P + p0 + pl] = v;
    }
}

// ---------------- fused lift_net + lifting add ----------------
// out = oth + sign * tanh( W2 @ relu( W1 *conv4,reflect(2,1)* x ) + b2 )
// x viewed as (B, 64, R, L) via strides; conv along L. L in {16,32}. grid (R*L/64, 1, B).
__global__ __launch_bounds__(256) void lift_net_kernel(
    const float* __restrict__ xin, int x_sB, int x_sC, int x_sR, int x_sA,
    const float* __restrict__ oth, int o_sB, int o_sC, int o_sR, int o_sA,
    float* __restrict__ outp, int u_sB, int u_sC, int u_sR, int u_sA,
    const float* __restrict__ w1, const float* __restrict__ b1,
    const float* __restrict__ w2, const float* __restrict__ b2,
    int R, int L, float sign)
{
    __shared__ float xsm[4864];   // 64 * rpb * (L+3)
    __shared__ float hsm[8192];   // 128 x 64
    __shared__ float ws1[4096];   // 128oc x (8c x 4t)
    __shared__ float w2s[8192];   // 64 x 128
    int t = threadIdx.x;
    int b = blockIdx.z;
    int rpb = 64 / L;
    int row0 = blockIdx.x * rpb;
    int Lp = L + 3;
    int total = 64 * rpb * Lp;
    for (int idx = t; idx < total; idx += 256) {
        int c = idx / (rpb * Lp);
        int rem = idx - c * rpb * Lp;
        int rr_l = rem / Lp;
        int q = rem - rr_l * Lp;
        int s = q - 2;
        s = (s < 0) ? -s : s;
        if (s >= L) s = 2 * L - 2 - s;
        xsm[idx] = xin[b * x_sB + c * x_sC + (row0 + rr_l) * x_sR + s * x_sA];
    }
    for (int idx = t; idx < 8192; idx += 256) w2s[idx] = w2[idx];

    int g = t & 63, ocg = t >> 6;
    int rl = g / L, jl = g - rl * L;
    float acc1[32] = {};
    for (int cc = 0; cc < 8; cc++) {
        __syncthreads();
        #pragma unroll
        for (int u = 0; u < 16; u++) {
            int idx = t + u * 256;
            int oc = idx >> 5, r = idx & 31;
            ws1[idx] = w1[oc * 256 + cc * 32 + r];
        }
        __syncthreads();
        #pragma unroll
        for (int c8 = 0; c8 < 8; c8++) {
            int c = cc * 8 + c8;
            const float* xr = &xsm[(c * rpb + rl) * Lp + jl];
            float x0 = xr[0], x1 = xr[1], x2 = xr[2], x3 = xr[3];
            #pragma unroll
            for (int k = 0; k < 32; k++) {
                const float* wr = &ws1[(ocg * 32 + k) * 32 + c8 * 4];
                acc1[k] += wr[0] * x0 + wr[1] * x1 + wr[2] * x2 + wr[3] * x3;
            }
        }
    }
    #pragma unroll
    for (int k = 0; k < 32; k++) {
        int oc = ocg * 32 + k;
        hsm[oc * 64 + g] = fmaxf(acc1[k] + b1[oc], 0.f);
    }
    __syncthreads();
    float acc2[16] = {};
    #pragma unroll 4
    for (int h = 0; h < 128; h++) {
        float hv = hsm[h * 64 + g];
        #pragma unroll
        for (int kk = 0; kk < 16; kk++)
            acc2[kk] += w2s[(ocg * 16 + kk) * 128 + h] * hv;
    }
    int rg = row0 + rl;
    #pragma unroll
    for (int kk = 0; kk < 16; kk++) {
        int o = ocg * 16 + kk;
        float v = oth[b * o_sB + o * o_sC + rg * o_sR + jl * o_sA]
                + sign * tanhf(acc2[kk] + b2[o]);
        outp[b * u_sB + o * u_sC + rg * u_sR + jl * u_sA] = v;
    }
}

// ---------------- ConvTranspose2d(k=4,s=2,p=1) + BN + optional residual ----------------
// w layout (Cin, Cout, 4, 4). grid (Hout*Wout/64, Cout/64, B), 256 threads.
__global__ __launch_bounds__(256) void convt_bn_kernel(
    const float* __restrict__ x, const float* __restrict__ w, const float* __restrict__ bias,
    const float* __restrict__ g, const float* __restrict__ be,
    const float* __restrict__ mu, const float* __restrict__ va,
    const float* __restrict__ res, float* __restrict__ out,
    int Cin, int Cout, int Hin, int Win, int o_off, int OCtot)
{
    __shared__ float xsh[16][3][34];
    __shared__ float wsh[16][64][16];
    int Wout = 2 * Win, Hout = 2 * Hin;
    int rpb = 64 / Wout;
    int nr = rpb + 1;
    int t = threadIdx.x;
    int b = blockIdx.z;
    int o0 = blockIdx.y * 64;
    int y0 = blockIdx.x * rpb;
    int iy0 = (y0 >= 1) ? (y0 - 1) / 2 : -1;
    int pos = t & 63, og = t >> 6;
    int lx = pos % Wout, dy = pos / Wout;
    int y = y0 + dy;
    int kyb = 1 - (y & 1), kxb = 1 - (lx & 1);
    float acc[16] = {};
    int Wp = Win + 2;
    int xtotal = 16 * nr * Wp;
    for (int cc = 0; cc < Cin; cc += 16) {
        __syncthreads();
        for (int idx = t; idx < xtotal; idx += 256) {
            int cl = idx / (nr * Wp);
            int rem = idx - cl * nr * Wp;
            int rl2 = rem / Wp;
            int q = rem - rl2 * Wp;
            int iy = iy0 + rl2, ix = q - 1;
            float v = 0.f;
            if (iy >= 0 && iy < Hin && ix >= 0 && ix < Win)
                v = x[((b * Cin + cc + cl) * Hin + iy) * Win + ix];
            xsh[cl][rl2][q] = v;
        }
        for (int idx = t; idx < 16384; idx += 256) {
            int cl = idx >> 10;
            int rem = idx & 1023;
            int ol = rem >> 4, tap = rem & 15;
            wsh[cl][ol][tap] = w[((cc + cl) * Cout + o0 + ol) * 16 + tap];
        }
        __syncthreads();
        #pragma unroll
        for (int cl = 0; cl < 16; cl++) {
            #pragma unroll
            for (int kyi = 0; kyi < 2; kyi++) {
                int ky = kyb + 2 * kyi;
                int iy = (y + 1 - ky) / 2;      // exact even division (works for negatives)
                int rl2 = iy - iy0;
                #pragma unroll
                for (int kxi = 0; kxi < 2; kxi++) {
                    int kx = kxb + 2 * kxi;
                    int ix = (lx + 1 - kx) / 2;
                    float xv = xsh[cl][rl2][ix + 1];
                    int wt = ky * 4 + kx;
                    #pragma unroll
                    for (int oo = 0; oo < 16; oo++)
                        acc[oo] += wsh[cl][og * 16 + oo][wt] * xv;
                }
            }
        }
    }
    #pragma unroll
    for (int oo = 0; oo < 16; oo++) {
        int o = o0 + og * 16 + oo;
        float s = g[o] * rsqrtf(va[o] + EPSV);
        float v = (acc[oo] + bias[o]) * s + (be[o] - mu[o] * s);
        if (res) v += res[((b * Cout + o) * Hout + y) * Wout + lx];
        out[((b * OCtot + o_off + o) * Hout + y) * Wout + lx] = v;
    }
}

// ---------------- depthwise 3x3, pad 1, on (B,256,64,64) ----------------
__global__ __launch_bounds__(256) void dw3x3_kernel(
    const float* __restrict__ x, const float* __restrict__ w, const float* __restrict__ bias,
    const float* __restrict__ scale, float* __restrict__ out, int relu_out)
{
    int c = blockIdx.y, b = blockIdx.z;
    int pix = blockIdx.x * 256 + threadIdx.x;
    int y = pix >> 6, xc = pix & 63;
    const float* xp = x + (b * 256 + c) * 4096;
    const float* wc = w + c * 9;
    float acc = bias[c];
    #pragma unroll
    for (int ky = 0; ky < 3; ky++) {
        int yy = y + ky - 1;
        if (yy < 0 || yy > 63) continue;
        #pragma unroll
        for (int kx = 0; kx < 3; kx++) {
            int xx = xc + kx - 1;
            if (xx < 0 || xx > 63) continue;
            acc += wc[ky * 3 + kx] * xp[yy * 64 + xx];
        }
    }
    if (relu_out) acc = fmaxf(acc, 0.f);
    if (scale) acc *= scale[c];
    out[(b * 256 + c) * 4096 + pix] = acc;
}

// ---------------- final gather + residual ----------------
__global__ __launch_bounds__(256) void gather_add_kernel(
    const float* __restrict__ tok, const int* __restrict__ idx,
    const float* __restrict__ t2, float* __restrict__ out)
{
    int i = blockIdx.x * 256 + threadIdx.x;      // over B*C*N
    int bc = i >> 13;
    out[i] = tok[i] + t2[(bc << 12) + idx[i]];
}

extern "C" void kernel_launch(void* const* d_in, const int* in_sizes, int n_in,
                              void* d_out, int out_size, void* d_ws, size_t ws_size,
                              hipStream_t stream)
{
    const float* tokens = (const float*)d_in[0];
    const float* fm     = (const float*)d_in[1];
    const int*   infl   = (const int*)d_in[2];
    const float* bng = (const float*)d_in[3];
    const float* bnb = (const float*)d_in[4];
    const float* bnm = (const float*)d_in[5];
    const float* bnv = (const float*)d_in[6];
    const float* red_w = (const float*)d_in[7];
    const float* red_b = (const float*)d_in[8];
    const float* lw1 = (const float*)d_in[9];
    const float* lb1 = (const float*)d_in[10];
    const float* lw2 = (const float*)d_in[11];
    const float* lb2 = (const float*)d_in[12];
    const float* f2w1 = (const float*)d_in[13];
    const float* f2b1 = (const float*)d_in[14];
    const float* f2w2 = (const float*)d_in[15];
    const float* f2b2 = (const float*)d_in[16];
    const float* ct2w = (const float*)d_in[17];
    const float* ct2b = (const float*)d_in[18];
    const float* bn2g = (const float*)d_in[19];
    const float* bn2b = (const float*)d_in[20];
    const float* bn2m = (const float*)d_in[21];
    const float* bn2v = (const float*)d_in[22];
    const float* f1w1 = (const float*)d_in[23];
    const float* f1b1 = (const float*)d_in[24];
    const float* f1w2 = (const float*)d_in[25];
    const float* f1b2 = (const float*)d_in[26];
    const float* ct1w = (const float*)d_in[27];
    const float* ct1b = (const float*)d_in[28];
    const float* bn1g = (const float*)d_in[29];
    const float* bn1b = (const float*)d_in[30];
    const float* bn1m = (const float*)d_in[31];
    const float* bn1v = (const float*)d_in[32];
    const float* dw1w = (const float*)d_in[33];
    const float* dw1b = (const float*)d_in[34];
    const float* dw2w = (const float*)d_in[35];
    const float* dw2b = (const float*)d_in[36];
    const float* scw  = (const float*)d_in[37];

    float* ws = (float*)d_ws;
    float* rbn   = ws + 0;          // 4194304
    float* rgrid = ws + 4194304;    // 2097152
    float* rr    = ws + 6291456;    // 524288
    float* c1    = ws + 6815744;    // 262144
    float* d1    = ws + 7077888;    // 262144
    float* c2    = ws + 7340032;    // 65536
    float* d2    = ws + 7405568;    // 65536
    float* x2    = ws + 7471104;    // 131072
    float* g2    = ws + 7602176;    // 131072
    float* y2p   = ws + 7733248;    // 131072
    float* x1    = ws + 7864320;    // 786432
    float* g1    = ws + 8650752;    // 524288
    float* y1p   = ws + 9175040;    // 524288
    float* r2    = ws + 9699328;    // 2097152
    float* t1    = ws + 0;          // reuse rbn (dead after flatten_gemm)
    float* t2    = ws + 2097152;    // reuse rbn

    // 1. BN
    bn_affine_kernel<<<4096, 256, 0, stream>>>((const float4*)tokens, (float4*)rbn,
                                               bng, bnb, bnm, bnv);
    // 2. flatten einsum
    flatten_gemm<<<dim3(32, 4, 2), 512, 0, stream>>>(rbn, fm, rgrid);
    // 3. reduce 1x1 (256->64)
    conv1x1_kernel<<<dim3(64, 1, 2), 256, 0, stream>>>(rgrid, red_w, red_b, rr,
                                                       256, 64, 4096, 0);

    auto lift = [&](const float* xin, int xsB, int xsC, int xsR, int xsA,
                    const float* ot, int osB, int osC, int osR, int osA,
                    float* op, int usB, int usC, int usR, int usA,
                    int lvl, int sch, int net, int R, int L, float sign) {
        int widx = (lvl * 2 + sch) * 2 + net;
        lift_net_kernel<<<dim3(R * L / 64, 1, 2), 256, 0, stream>>>(
            xin, xsB, xsC, xsR, xsA, ot, osB, osC, osR, osA, op, usB, usC, usR, usA,
            lw1 + widx * 32768, lb1 + widx * 128, lw2 + widx * 8192, lb2 + widx * 64,
            R, L, sign);
    };

    // ---- level 1, horizontal (rr: B,64,64,64) ----
    lift(rr,     262144, 4096, 64, 2,  rr + 1, 262144, 4096, 64, 2,
         d1,     131072, 2048, 32, 1,  0, 0, 0, 64, 32, -1.f);
    lift(d1,     131072, 2048, 32, 1,  rr,     262144, 4096, 64, 2,
         c1,     131072, 2048, 32, 1,  0, 0, 1, 64, 32, +1.f);
    // ---- level 1, vertical on c1 -> LH1, LL1 (into x1 ch 64, 0) ----
    lift(c1,      131072, 2048, 1, 64,  c1 + 32, 131072, 2048, 1, 64,
         x1 + 65536, 393216, 1024, 1, 32,  0, 1, 0, 32, 32, -1.f);
    lift(x1 + 65536, 393216, 1024, 1, 32,  c1, 131072, 2048, 1, 64,
         x1 + 0,     393216, 1024, 1, 32,  0, 1, 1, 32, 32, +1.f);
    // ---- level 1, vertical on d1 -> HH1, HL1 (into x1 ch 192, 128) ----
    lift(d1,      131072, 2048, 1, 64,  d1 + 32, 131072, 2048, 1, 64,
         x1 + 196608, 393216, 1024, 1, 32,  0, 1, 0, 32, 32, -1.f);
    lift(x1 + 196608, 393216, 1024, 1, 32,  d1, 131072, 2048, 1, 64,
         x1 + 131072, 393216, 1024, 1, 32,  0, 1, 1, 32, 32, +1.f);
    // ---- level 2, horizontal on LL1 (view in x1, (B,64,32,32)) ----
    lift(x1,     393216, 1024, 32, 2,  x1 + 1, 393216, 1024, 32, 2,
         d2,     65536, 512, 16, 1,   1, 0, 0, 32, 16, -1.f);
    lift(d2,     65536, 512, 16, 1,   x1,     393216, 1024, 32, 2,
         c2,     65536, 512, 16, 1,   1, 0, 1, 32, 16, +1.f);
    // ---- level 2, vertical on c2 -> LH2, LL2 (into x2 ch 64, 0) ----
    lift(c2,      65536, 512, 1, 32,  c2 + 16, 65536, 512, 1, 32,
         x2 + 16384, 65536, 256, 1, 16,  1, 1, 0, 16, 16, -1.f);
    lift(x2 + 16384, 65536, 256, 1, 16,  c2, 65536, 512, 1, 32,
         x2 + 0,     65536, 256, 1, 16,  1, 1, 1, 16, 16, +1.f);
    // ---- level 2, vertical on d2 -> HH2, HL2 (into x2 ch 192, 128) ----
    lift(d2,      65536, 512, 1, 32,  d2 + 16, 65536, 512, 1, 32,
         x2 + 49152, 65536, 256, 1, 16,  1, 1, 0, 16, 16, -1.f);
    lift(x2 + 49152, 65536, 256, 1, 16,  d2, 65536, 512, 1, 32,
         x2 + 32768, 65536, 256, 1, 16,  1, 1, 1, 16, 16, +1.f);

    // ---- ff2 + ct2 + bn2 -> x1 channels 256..383 ----
    conv1x1_kernel<<<dim3(4, 4, 2), 256, 0, stream>>>(x2, f2w1, f2b1, g2, 256, 256, 256, 2);
    conv1x1_kernel<<<dim3(4, 4, 2), 256, 0, stream>>>(g2, f2w2, f2b2, y2p, 256, 256, 256, 0);
    convt_bn_kernel<<<dim3(16, 2, 2), 256, 0, stream>>>(y2p, ct2w, ct2b,
        bn2g, bn2b, bn2m, bn2v, (const float*)nullptr, x1, 256, 128, 16, 16, 256, 384);

    // ---- ff1 + ct1 + bn1 + residual(rgrid) -> r2 ----
    conv1x1_kernel<<<dim3(16, 4, 2), 256, 0, stream>>>(x1, f1w1, f1b1, g1, 384, 256, 1024, 2);
    conv1x1_kernel<<<dim3(16, 4, 2), 256, 0, stream>>>(g1, f1w2, f1b2, y1p, 256, 256, 1024, 0);
    convt_bn_kernel<<<dim3(64, 4, 2), 256, 0, stream>>>(y1p, ct1w, ct1b,
        bn1g, bn1b, bn1m, bn1v, rgrid, r2, 256, 256, 32, 32, 0, 256);

    // ---- depthwise convs + scale ----
    dw3x3_kernel<<<dim3(16, 256, 2), 256, 0, stream>>>(r2, dw1w, dw1b,
        (const float*)nullptr, t1, 1);
    dw3x3_kernel<<<dim3(16, 256, 2), 256, 0, stream>>>(t1, dw2w, dw2b, scw, t2, 0);

    // ---- inflate gather + residual ----
    gather_add_kernel<<<16384, 256, 0, stream>>>(tokens, infl, t2, (float*)d_out);
}

// Round 2
// 2045.841 us; speedup vs baseline: 1.2024x; 1.2024x over previous
//
#include <hip/hip_runtime.h>
#include <math.h>

#define EPSV 1e-5f

typedef __attribute__((ext_vector_type(8))) short bf16x8;
typedef __attribute__((ext_vector_type(4))) float f32x4;

__device__ inline unsigned short f2bf(float f) {
    unsigned u = __float_as_uint(f);
    unsigned r = (u + 0x7fffu + ((u >> 16) & 1u)) >> 16;
    return (unsigned short)r;
}

__device__ inline void gload_lds16(const void* g, void* l) {
    __builtin_amdgcn_global_load_lds(
        (const __attribute__((address_space(1))) void*)g,
        (__attribute__((address_space(3))) void*)l, 16, 0, 0);
}

// ---------------- BN over tokens (B,C,N) -> bf16 ----------------
__global__ __launch_bounds__(256) void bn_to_bf16_kernel(
    const float4* __restrict__ x, ushort4* __restrict__ y,
    const float* __restrict__ g, const float* __restrict__ be,
    const float* __restrict__ mu, const float* __restrict__ va)
{
    int i = blockIdx.x * 256 + threadIdx.x;      // over B*C*N/4
    int c = (i >> 11) & 255;
    float s = g[c] * rsqrtf(va[c] + EPSV);
    float t = be[c] - mu[c] * s;
    float4 v = x[i];
    ushort4 h;
    h.x = f2bf(v.x * s + t); h.y = f2bf(v.y * s + t);
    h.z = f2bf(v.z * s + t); h.w = f2bf(v.w * s + t);
    y[i] = h;
}

// ---------------- MFMA flatten einsum ----------------
// C[b,c,m] = sum_k Abf[b,c,k] * Bm[b,m,k];  A bf16 (256x8192), B f32 (4096x8192)
// BM=256 (all c), BN=64, BK=32, K-split 2. grid (64,1,4) = (n-tile, 1, b*2+ks). 256 thr.
__global__ __launch_bounds__(256) void flatten_gemm_mfma(
    const unsigned short* __restrict__ A, const float* __restrict__ Bm,
    float* __restrict__ P0, float* __restrict__ P1)
{
    __shared__ unsigned short AS[2][256 * 32];   // 2 x 16 KB, swizzled
    __shared__ unsigned short BS[2][64 * 32];    // 2 x 4 KB, swizzled
    int t = threadIdx.x;
    int wid = t >> 6, lane = t & 63;
    int n0 = blockIdx.x * 64;
    int ks = blockIdx.z & 1, b = blockIdx.z >> 1;
    const unsigned short* Ab = A + b * (256 * 8192);
    const float* Bb = Bm + b * (4096 * 8192) + n0 * 8192;
    int k0 = ks * 4096;
    int brow = t >> 3, bc8 = t & 7;              // B-stage: rows brow, brow+32; f32 chunk bc8

    f32x4 acc[4][4] = {};

    // ---- prologue: stage A[0] into AS[0]; load B[0] regs ----
    #pragma unroll
    for (int j = 0; j < 4; ++j) {
        int d16 = (wid * 4 + j) * 64 + lane;
        int row = d16 >> 2;
        int ch = (d16 & 3) ^ ((row >> 1) & 3);
        gload_lds16(Ab + row * 8192 + k0 + ch * 8, &AS[0][(wid * 4 + j) * 512]);
    }
    float4 breg0 = *(const float4*)(Bb + brow * 8192 + k0 + bc8 * 4);
    float4 breg1 = *(const float4*)(Bb + (brow + 32) * 8192 + k0 + bc8 * 4);
    __syncthreads();

    for (int it = 0; it < 128; ++it) {
        int cur = it & 1;
        // ---- write B[it] (cvt f32->bf16) into BS[cur] ----
        {
            int ch16 = (bc8 >> 1) ^ ((brow >> 1) & 3);
            ushort4 h;
            h.x = f2bf(breg0.x); h.y = f2bf(breg0.y); h.z = f2bf(breg0.z); h.w = f2bf(breg0.w);
            *reinterpret_cast<ushort4*>(&BS[cur][brow * 32 + ch16 * 8 + (bc8 & 1) * 4]) = h;
            int r2 = brow + 32;
            int ch16b = (bc8 >> 1) ^ ((r2 >> 1) & 3);
            ushort4 h2;
            h2.x = f2bf(breg1.x); h2.y = f2bf(breg1.y); h2.z = f2bf(breg1.z); h2.w = f2bf(breg1.w);
            *reinterpret_cast<ushort4*>(&BS[cur][r2 * 32 + ch16b * 8 + (bc8 & 1) * 4]) = h2;
        }
        __syncthreads();   // A[it]+B[it] visible (drains glds issued last iter)

        // ---- prefetch next tile ----
        if (it < 127) {
            int kn = k0 + (it + 1) * 32;
            #pragma unroll
            for (int j = 0; j < 4; ++j) {
                int d16 = (wid * 4 + j) * 64 + lane;
                int row = d16 >> 2;
                int ch = (d16 & 3) ^ ((row >> 1) & 3);
                gload_lds16(Ab + row * 8192 + kn + ch * 8, &AS[cur ^ 1][(wid * 4 + j) * 512]);
            }
            breg0 = *(const float4*)(Bb + brow * 8192 + kn + bc8 * 4);
            breg1 = *(const float4*)(Bb + (brow + 32) * 8192 + kn + bc8 * 4);
        }

        // ---- fragments + MFMA ----
        int l15 = lane & 15, kc = lane >> 4;
        bf16x8 af[4], bfr[4];
        #pragma unroll
        for (int mf = 0; mf < 4; ++mf) {
            int row = wid * 64 + mf * 16 + l15;
            int ch = kc ^ ((row >> 1) & 3);
            af[mf] = *reinterpret_cast<const bf16x8*>(&AS[cur][row * 32 + ch * 8]);
        }
        #pragma unroll
        for (int nf = 0; nf < 4; ++nf) {
            int row = nf * 16 + l15;
            int ch = kc ^ ((row >> 1) & 3);
            bfr[nf] = *reinterpret_cast<const bf16x8*>(&BS[cur][row * 32 + ch * 8]);
        }
        #pragma unroll
        for (int mf = 0; mf < 4; ++mf)
            #pragma unroll
            for (int nf = 0; nf < 4; ++nf)
                acc[mf][nf] = __builtin_amdgcn_mfma_f32_16x16x32_bf16(
                    af[mf], bfr[nf], acc[mf][nf], 0, 0, 0);
        __syncthreads();   // all reads of buffers[cur] done before next overwrite
    }

    float* P = ks ? P1 : P0;
    float* Cb = P + (b * 256) * 4096 + n0;
    #pragma unroll
    for (int mf = 0; mf < 4; ++mf) {
        int rbase = wid * 64 + mf * 16 + (lane >> 4) * 4;
        #pragma unroll
        for (int nf = 0; nf < 4; ++nf) {
            int col = nf * 16 + (lane & 15);
            #pragma unroll
            for (int r = 0; r < 4; ++r)
                Cb[(rbase + r) * 4096 + col] = acc[mf][nf][r];
        }
    }
}

// ---------------- sum of 2 K-split partials ----------------
__global__ __launch_bounds__(256) void add2_kernel(
    const float4* __restrict__ a, const float4* __restrict__ b, float4* __restrict__ o)
{
    int i = blockIdx.x * 256 + threadIdx.x;
    float4 x = a[i], y = b[i];
    x.x += y.x; x.y += y.y; x.z += y.z; x.w += y.w;
    o[i] = x;
}

// ---------------- generic 1x1 conv ----------------
__global__ __launch_bounds__(256) void conv1x1_kernel(
    const float* __restrict__ x, const float* __restrict__ w,
    const float* __restrict__ bias, float* __restrict__ out,
    int Cin, int Cout, int P, int act)
{
    __shared__ float xsm[64 * 64];
    __shared__ float wsm[64 * 64];
    int t = threadIdx.x;
    int b = blockIdx.z;
    int p0 = blockIdx.x * 64, o0 = blockIdx.y * 64;
    int pl = t & 63, og = t >> 6;
    float acc[16] = {};
    for (int cc = 0; cc < Cin; cc += 64) {
        __syncthreads();
        #pragma unroll
        for (int u = 0; u < 16; u++) {
            int idx = t + u * 256;
            int cl = idx >> 6, q = idx & 63;
            xsm[idx] = x[(b * Cin + cc + cl) * P + p0 + q];
            wsm[idx] = w[(o0 + cl) * Cin + cc + q];
        }
        __syncthreads();
        #pragma unroll 8
        for (int c = 0; c < 64; c++) {
            float xv = xsm[c * 64 + pl];
            #pragma unroll
            for (int oo = 0; oo < 16; oo++)
                acc[oo] += wsm[(og + (oo << 2)) * 64 + c] * xv;
        }
    }
    #pragma unroll
    for (int oo = 0; oo < 16; oo++) {
        int o = o0 + og + (oo << 2);
        float v = acc[oo] + bias[o];
        if (act == 1) v = fmaxf(v, 0.f);
        else if (act == 2) v = 0.5f * v * (1.f + erff(v * 0.70710678118f));
        out[(b * Cout + o) * P + p0 + pl] = v;
    }
}

// ---------------- fused lift_net + lifting add ----------------
__global__ __launch_bounds__(256) void lift_net_kernel(
    const float* __restrict__ xin, int x_sB, int x_sC, int x_sR, int x_sA,
    const float* __restrict__ oth, int o_sB, int o_sC, int o_sR, int o_sA,
    float* __restrict__ outp, int u_sB, int u_sC, int u_sR, int u_sA,
    const float* __restrict__ w1, const float* __restrict__ b1,
    const float* __restrict__ w2, const float* __restrict__ b2,
    int R, int L, float sign)
{
    __shared__ float xsm[4864];
    __shared__ float hsm[8192];
    __shared__ float ws1[4096];
    __shared__ float w2s[8192];
    int t = threadIdx.x;
    int b = blockIdx.z;
    int rpb = 64 / L;
    int row0 = blockIdx.x * rpb;
    int Lp = L + 3;
    int total = 64 * rpb * Lp;
    for (int idx = t; idx < total; idx += 256) {
        int c = idx / (rpb * Lp);
        int rem = idx - c * rpb * Lp;
        int rr_l = rem / Lp;
        int q = rem - rr_l * Lp;
        int s = q - 2;
        s = (s < 0) ? -s : s;
        if (s >= L) s = 2 * L - 2 - s;
        xsm[idx] = xin[b * x_sB + c * x_sC + (row0 + rr_l) * x_sR + s * x_sA];
    }
    for (int idx = t; idx < 8192; idx += 256) w2s[idx] = w2[idx];

    int g = t & 63, ocg = t >> 6;
    int rl = g / L, jl = g - rl * L;
    float acc1[32] = {};
    for (int cc = 0; cc < 8; cc++) {
        __syncthreads();
        #pragma unroll
        for (int u = 0; u < 16; u++) {
            int idx = t + u * 256;
            int oc = idx >> 5, r = idx & 31;
            ws1[idx] = w1[oc * 256 + cc * 32 + r];
        }
        __syncthreads();
        #pragma unroll
        for (int c8 = 0; c8 < 8; c8++) {
            int c = cc * 8 + c8;
            const float* xr = &xsm[(c * rpb + rl) * Lp + jl];
            float x0 = xr[0], x1 = xr[1], x2 = xr[2], x3 = xr[3];
            #pragma unroll
            for (int k = 0; k < 32; k++) {
                const float* wr = &ws1[(ocg * 32 + k) * 32 + c8 * 4];
                acc1[k] += wr[0] * x0 + wr[1] * x1 + wr[2] * x2 + wr[3] * x3;
            }
        }
    }
    #pragma unroll
    for (int k = 0; k < 32; k++) {
        int oc = ocg * 32 + k;
        hsm[oc * 64 + g] = fmaxf(acc1[k] + b1[oc], 0.f);
    }
    __syncthreads();
    float acc2[16] = {};
    #pragma unroll 4
    for (int h = 0; h < 128; h++) {
        float hv = hsm[h * 64 + g];
        #pragma unroll
        for (int kk = 0; kk < 16; kk++)
            acc2[kk] += w2s[(ocg * 16 + kk) * 128 + h] * hv;
    }
    int rg = row0 + rl;
    #pragma unroll
    for (int kk = 0; kk < 16; kk++) {
        int o = ocg * 16 + kk;
        float v = oth[b * o_sB + o * o_sC + rg * o_sR + jl * o_sA]
                + sign * tanhf(acc2[kk] + b2[o]);
        outp[b * u_sB + o * u_sC + rg * u_sR + jl * u_sA] = v;
    }
}

// ---------------- ConvTranspose2d(k=4,s=2,p=1) + BN + optional residual ----------------
__global__ __launch_bounds__(256) void convt_bn_kernel(
    const float* __restrict__ x, const float* __restrict__ w, const float* __restrict__ bias,
    const float* __restrict__ g, const float* __restrict__ be,
    const float* __restrict__ mu, const float* __restrict__ va,
    const float* __restrict__ res, float* __restrict__ out,
    int Cin, int Cout, int Hin, int Win, int o_off, int OCtot)
{
    __shared__ float xsh[16][3][34];
    __shared__ float wsh[16][64][16];
    int Wout = 2 * Win, Hout = 2 * Hin;
    int rpb = 64 / Wout;
    int nr = rpb + 1;
    int t = threadIdx.x;
    int b = blockIdx.z;
    int o0 = blockIdx.y * 64;
    int y0 = blockIdx.x * rpb;
    int iy0 = (y0 >= 1) ? (y0 - 1) / 2 : -1;
    int pos = t & 63, og = t >> 6;
    int lx = pos % Wout, dy = pos / Wout;
    int y = y0 + dy;
    int kyb = 1 - (y & 1), kxb = 1 - (lx & 1);
    float acc[16] = {};
    int Wp = Win + 2;
    int xtotal = 16 * nr * Wp;
    for (int cc = 0; cc < Cin; cc += 16) {
        __syncthreads();
        for (int idx = t; idx < xtotal; idx += 256) {
            int cl = idx / (nr * Wp);
            int rem = idx - cl * nr * Wp;
            int rl2 = rem / Wp;
            int q = rem - rl2 * Wp;
            int iy = iy0 + rl2, ix = q - 1;
            float v = 0.f;
            if (iy >= 0 && iy < Hin && ix >= 0 && ix < Win)
                v = x[((b * Cin + cc + cl) * Hin + iy) * Win + ix];
            xsh[cl][rl2][q] = v;
        }
        for (int idx = t; idx < 16384; idx += 256) {
            int cl = idx >> 10;
            int rem = idx & 1023;
            int ol = rem >> 4, tap = rem & 15;
            wsh[cl][ol][tap] = w[((cc + cl) * Cout + o0 + ol) * 16 + tap];
        }
        __syncthreads();
        #pragma unroll
        for (int cl = 0; cl < 16; cl++) {
            #pragma unroll
            for (int kyi = 0; kyi < 2; kyi++) {
                int ky = kyb + 2 * kyi;
                int iy = (y + 1 - ky) / 2;
                int rl2 = iy - iy0;
                #pragma unroll
                for (int kxi = 0; kxi < 2; kxi++) {
                    int kx = kxb + 2 * kxi;
                    int ix = (lx + 1 - kx) / 2;
                    float xv = xsh[cl][rl2][ix + 1];
                    int wt = ky * 4 + kx;
                    #pragma unroll
                    for (int oo = 0; oo < 16; oo++)
                        acc[oo] += wsh[cl][og * 16 + oo][wt] * xv;
                }
            }
        }
    }
    #pragma unroll
    for (int oo = 0; oo < 16; oo++) {
        int o = o0 + og * 16 + oo;
        float s = g[o] * rsqrtf(va[o] + EPSV);
        float v = (acc[oo] + bias[o]) * s + (be[o] - mu[o] * s);
        if (res) v += res[((b * Cout + o) * Hout + y) * Wout + lx];
        out[((b * OCtot + o_off + o) * Hout + y) * Wout + lx] = v;
    }
}

// ---------------- depthwise 3x3 ----------------
__global__ __launch_bounds__(256) void dw3x3_kernel(
    const float* __restrict__ x, const float* __restrict__ w, const float* __restrict__ bias,
    const float* __restrict__ scale, float* __restrict__ out, int relu_out)
{
    int c = blockIdx.y, b = blockIdx.z;
    int pix = blockIdx.x * 256 + threadIdx.x;
    int y = pix >> 6, xc = pix & 63;
    const float* xp = x + (b * 256 + c) * 4096;
    const float* wc = w + c * 9;
    float acc = bias[c];
    #pragma unroll
    for (int ky = 0; ky < 3; ky++) {
        int yy = y + ky - 1;
        if (yy < 0 || yy > 63) continue;
        #pragma unroll
        for (int kx = 0; kx < 3; kx++) {
            int xx = xc + kx - 1;
            if (xx < 0 || xx > 63) continue;
            acc += wc[ky * 3 + kx] * xp[yy * 64 + xx];
        }
    }
    if (relu_out) acc = fmaxf(acc, 0.f);
    if (scale) acc *= scale[c];
    out[(b * 256 + c) * 4096 + pix] = acc;
}

// ---------------- final gather + residual ----------------
__global__ __launch_bounds__(256) void gather_add_kernel(
    const float* __restrict__ tok, const int* __restrict__ idx,
    const float* __restrict__ t2, float* __restrict__ out)
{
    int i = blockIdx.x * 256 + threadIdx.x;
    int bc = i >> 13;
    out[i] = tok[i] + t2[(bc << 12) + idx[i]];
}

extern "C" void kernel_launch(void* const* d_in, const int* in_sizes, int n_in,
                              void* d_out, int out_size, void* d_ws, size_t ws_size,
                              hipStream_t stream)
{
    const float* tokens = (const float*)d_in[0];
    const float* fm     = (const float*)d_in[1];
    const int*   infl   = (const int*)d_in[2];
    const float* bng = (const float*)d_in[3];
    const float* bnb = (const float*)d_in[4];
    const float* bnm = (const float*)d_in[5];
    const float* bnv = (const float*)d_in[6];
    const float* red_w = (const float*)d_in[7];
    const float* red_b = (const float*)d_in[8];
    const float* lw1 = (const float*)d_in[9];
    const float* lb1 = (const float*)d_in[10];
    const float* lw2 = (const float*)d_in[11];
    const float* lb2 = (const float*)d_in[12];
    const float* f2w1 = (const float*)d_in[13];
    const float* f2b1 = (const float*)d_in[14];
    const float* f2w2 = (const float*)d_in[15];
    const float* f2b2 = (const float*)d_in[16];
    const float* ct2w = (const float*)d_in[17];
    const float* ct2b = (const float*)d_in[18];
    const float* bn2g = (const float*)d_in[19];
    const float* bn2b = (const float*)d_in[20];
    const float* bn2m = (const float*)d_in[21];
    const float* bn2v = (const float*)d_in[22];
    const float* f1w1 = (const float*)d_in[23];
    const float* f1b1 = (const float*)d_in[24];
    const float* f1w2 = (const float*)d_in[25];
    const float* f1b2 = (const float*)d_in[26];
    const float* ct1w = (const float*)d_in[27];
    const float* ct1b = (const float*)d_in[28];
    const float* bn1g = (const float*)d_in[29];
    const float* bn1b = (const float*)d_in[30];
    const float* bn1m = (const float*)d_in[31];
    const float* bn1v = (const float*)d_in[32];
    const float* dw1w = (const float*)d_in[33];
    const float* dw1b = (const float*)d_in[34];
    const float* dw2w = (const float*)d_in[35];
    const float* dw2b = (const float*)d_in[36];
    const float* scw  = (const float*)d_in[37];

    float* ws = (float*)d_ws;
    // layout (floats): total 11,796,480 = 47.19 MB (same as proven R1 footprint)
    unsigned short* Abf = (unsigned short*)ws;         // 4,194,304 bf16 = 2,097,152 slots
    float* p0    = ws + 2097152;    // 2,097,152
    float* p1    = ws + 4194304;    // 2,097,152
    float* rgrid = ws + 6291456;    // 2,097,152
    float* rr    = ws + 8388608;    // 524,288
    float* c1    = ws + 8912896;    // 262,144
    float* d1    = ws + 9175040;    // 262,144
    float* c2    = ws + 9437184;    // 65,536
    float* d2    = ws + 9502720;    // 65,536
    float* x2    = ws + 9568256;    // 131,072
    float* g2    = ws + 9699328;    // 131,072
    float* y2p   = ws + 9830400;    // 131,072
    float* x1    = ws + 9961472;    // 786,432
    float* g1    = ws + 10747904;   // 524,288
    float* y1p   = ws + 11272192;   // 524,288
    float* r2    = p0;              // p0 dead after add2
    float* t1    = p1;              // p1 dead after add2
    float* t2    = rgrid;           // rgrid dead after convt#1

    // 1. BN -> bf16
    bn_to_bf16_kernel<<<4096, 256, 0, stream>>>((const float4*)tokens, (ushort4*)Abf,
                                                bng, bnb, bnm, bnv);
    // 2. flatten einsum (MFMA, K-split 2) + reduce
    flatten_gemm_mfma<<<dim3(64, 1, 4), 256, 0, stream>>>(Abf, fm, p0, p1);
    add2_kernel<<<2048, 256, 0, stream>>>((const float4*)p0, (const float4*)p1, (float4*)rgrid);
    // 3. reduce 1x1 (256->64)
    conv1x1_kernel<<<dim3(64, 1, 2), 256, 0, stream>>>(rgrid, red_w, red_b, rr,
                                                       256, 64, 4096, 0);

    auto lift = [&](const float* xin, int xsB, int xsC, int xsR, int xsA,
                    const float* ot, int osB, int osC, int osR, int osA,
                    float* op, int usB, int usC, int usR, int usA,
                    int lvl, int sch, int net, int R, int L, float sign) {
        int widx = (lvl * 2 + sch) * 2 + net;
        lift_net_kernel<<<dim3(R * L / 64, 1, 2), 256, 0, stream>>>(
            xin, xsB, xsC, xsR, xsA, ot, osB, osC, osR, osA, op, usB, usC, usR, usA,
            lw1 + widx * 32768, lb1 + widx * 128, lw2 + widx * 8192, lb2 + widx * 64,
            R, L, sign);
    };

    // ---- level 1, horizontal (rr: B,64,64,64) ----
    lift(rr,     262144, 4096, 64, 2,  rr + 1, 262144, 4096, 64, 2,
         d1,     131072, 2048, 32, 1,  0, 0, 0, 64, 32, -1.f);
    lift(d1,     131072, 2048, 32, 1,  rr,     262144, 4096, 64, 2,
         c1,     131072, 2048, 32, 1,  0, 0, 1, 64, 32, +1.f);
    // ---- level 1, vertical on c1 -> LH1, LL1 ----
    lift(c1,      131072, 2048, 1, 64,  c1 + 32, 131072, 2048, 1, 64,
         x1 + 65536, 393216, 1024, 1, 32,  0, 1, 0, 32, 32, -1.f);
    lift(x1 + 65536, 393216, 1024, 1, 32,  c1, 131072, 2048, 1, 64,
         x1 + 0,     393216, 1024, 1, 32,  0, 1, 1, 32, 32, +1.f);
    // ---- level 1, vertical on d1 -> HH1, HL1 ----
    lift(d1,      131072, 2048, 1, 64,  d1 + 32, 131072, 2048, 1, 64,
         x1 + 196608, 393216, 1024, 1, 32,  0, 1, 0, 32, 32, -1.f);
    lift(x1 + 196608, 393216, 1024, 1, 32,  d1, 131072, 2048, 1, 64,
         x1 + 131072, 393216, 1024, 1, 32,  0, 1, 1, 32, 32, +1.f);
    // ---- level 2, horizontal on LL1 ----
    lift(x1,     393216, 1024, 32, 2,  x1 + 1, 393216, 1024, 32, 2,
         d2,     65536, 512, 16, 1,   1, 0, 0, 32, 16, -1.f);
    lift(d2,     65536, 512, 16, 1,   x1,     393216, 1024, 32, 2,
         c2,     65536, 512, 16, 1,   1, 0, 1, 32, 16, +1.f);
    // ---- level 2, vertical on c2 -> LH2, LL2 ----
    lift(c2,      65536, 512, 1, 32,  c2 + 16, 65536, 512, 1, 32,
         x2 + 16384, 65536, 256, 1, 16,  1, 1, 0, 16, 16, -1.f);
    lift(x2 + 16384, 65536, 256, 1, 16,  c2, 65536, 512, 1, 32,
         x2 + 0,     65536, 256, 1, 16,  1, 1, 1, 16, 16, +1.f);
    // ---- level 2, vertical on d2 -> HH2, HL2 ----
    lift(d2,      65536, 512, 1, 32,  d2 + 16, 65536, 512, 1, 32,
         x2 + 49152, 65536, 256, 1, 16,  1, 1, 0, 16, 16, -1.f);
    lift(x2 + 49152, 65536, 256, 1, 16,  d2, 65536, 512, 1, 32,
         x2 + 32768, 65536, 256, 1, 16,  1, 1, 1, 16, 16, +1.f);

    // ---- ff2 + ct2 + bn2 -> x1 channels 256..383 ----
    conv1x1_kernel<<<dim3(4, 4, 2), 256, 0, stream>>>(x2, f2w1, f2b1, g2, 256, 256, 256, 2);
    conv1x1_kernel<<<dim3(4, 4, 2), 256, 0, stream>>>(g2, f2w2, f2b2, y2p, 256, 256, 256, 0);
    convt_bn_kernel<<<dim3(16, 2, 2), 256, 0, stream>>>(y2p, ct2w, ct2b,
        bn2g, bn2b, bn2m, bn2v, (const float*)nullptr, x1, 256, 128, 16, 16, 256, 384);

    // ---- ff1 + ct1 + bn1 + residual(rgrid) -> r2 ----
    conv1x1_kernel<<<dim3(16, 4, 2), 256, 0, stream>>>(x1, f1w1, f1b1, g1, 384, 256, 1024, 2);
    conv1x1_kernel<<<dim3(16, 4, 2), 256, 0, stream>>>(g1, f1w2, f1b2, y1p, 256, 256, 1024, 0);
    convt_bn_kernel<<<dim3(64, 4, 2), 256, 0, stream>>>(y1p, ct1w, ct1b,
        bn1g, bn1b, bn1m, bn1v, rgrid, r2, 256, 256, 32, 32, 0, 256);

    // ---- depthwise convs + scale ----
    dw3x3_kernel<<<dim3(16, 256, 2), 256, 0, stream>>>(r2, dw1w, dw1b,
        (const float*)nullptr, t1, 1);
    dw3x3_kernel<<<dim3(16, 256, 2), 256, 0, stream>>>(t1, dw2w, dw2b, scw, t2, 0);

    // ---- inflate gather + residual ----
    gather_add_kernel<<<16384, 256, 0, stream>>>(tokens, infl, t2, (float*)d_out);
}

// Round 3
// 1397.887 us; speedup vs baseline: 1.7597x; 1.4635x over previous
//
#include <hip/hip_runtime.h>
#include <math.h>

#define EPSV 1e-5f

typedef __attribute__((ext_vector_type(8))) short bf16x8;
typedef __attribute__((ext_vector_type(4))) float f32x4;
typedef __attribute__((ext_vector_type(8))) unsigned short u16x8;

__device__ inline unsigned short f2bf(float f) {
    unsigned u = __float_as_uint(f);
    unsigned r = (u + 0x7fffu + ((u >> 16) & 1u)) >> 16;
    return (unsigned short)r;
}

__device__ inline void gload_lds16(const void* g, void* l) {
    __builtin_amdgcn_global_load_lds(
        (const __attribute__((address_space(1))) void*)g,
        (__attribute__((address_space(3))) void*)l, 16, 0, 0);
}

// ---------------- BN over tokens (B,C,N) -> bf16 ----------------
__global__ __launch_bounds__(256) void bn_to_bf16_kernel(
    const float4* __restrict__ x, ushort4* __restrict__ y,
    const float* __restrict__ g, const float* __restrict__ be,
    const float* __restrict__ mu, const float* __restrict__ va)
{
    int i = blockIdx.x * 256 + threadIdx.x;
    int c = (i >> 11) & 255;
    float s = g[c] * rsqrtf(va[c] + EPSV);
    float t = be[c] - mu[c] * s;
    float4 v = x[i];
    ushort4 h;
    h.x = f2bf(v.x * s + t); h.y = f2bf(v.y * s + t);
    h.z = f2bf(v.z * s + t); h.w = f2bf(v.w * s + t);
    y[i] = h;
}

// ---------------- MFMA flatten einsum (unchanged from R2) ----------------
__global__ __launch_bounds__(256) void flatten_gemm_mfma(
    const unsigned short* __restrict__ A, const float* __restrict__ Bm,
    float* __restrict__ P0, float* __restrict__ P1)
{
    __shared__ __align__(16) unsigned short AS[2][256 * 32];
    __shared__ __align__(16) unsigned short BS[2][64 * 32];
    int t = threadIdx.x;
    int wid = t >> 6, lane = t & 63;
    int n0 = blockIdx.x * 64;
    int ks = blockIdx.z & 1, b = blockIdx.z >> 1;
    const unsigned short* Ab = A + b * (256 * 8192);
    const float* Bb = Bm + b * (4096 * 8192) + n0 * 8192;
    int k0 = ks * 4096;
    int brow = t >> 3, bc8 = t & 7;

    f32x4 acc[4][4] = {};

    #pragma unroll
    for (int j = 0; j < 4; ++j) {
        int d16 = (wid * 4 + j) * 64 + lane;
        int row = d16 >> 2;
        int ch = (d16 & 3) ^ ((row >> 1) & 3);
        gload_lds16(Ab + row * 8192 + k0 + ch * 8, &AS[0][(wid * 4 + j) * 512]);
    }
    float4 breg0 = *(const float4*)(Bb + brow * 8192 + k0 + bc8 * 4);
    float4 breg1 = *(const float4*)(Bb + (brow + 32) * 8192 + k0 + bc8 * 4);
    __syncthreads();

    for (int it = 0; it < 128; ++it) {
        int cur = it & 1;
        {
            int ch16 = (bc8 >> 1) ^ ((brow >> 1) & 3);
            ushort4 h;
            h.x = f2bf(breg0.x); h.y = f2bf(breg0.y); h.z = f2bf(breg0.z); h.w = f2bf(breg0.w);
            *reinterpret_cast<ushort4*>(&BS[cur][brow * 32 + ch16 * 8 + (bc8 & 1) * 4]) = h;
            int r2 = brow + 32;
            int ch16b = (bc8 >> 1) ^ ((r2 >> 1) & 3);
            ushort4 h2;
            h2.x = f2bf(breg1.x); h2.y = f2bf(breg1.y); h2.z = f2bf(breg1.z); h2.w = f2bf(breg1.w);
            *reinterpret_cast<ushort4*>(&BS[cur][r2 * 32 + ch16b * 8 + (bc8 & 1) * 4]) = h2;
        }
        __syncthreads();

        if (it < 127) {
            int kn = k0 + (it + 1) * 32;
            #pragma unroll
            for (int j = 0; j < 4; ++j) {
                int d16 = (wid * 4 + j) * 64 + lane;
                int row = d16 >> 2;
                int ch = (d16 & 3) ^ ((row >> 1) & 3);
                gload_lds16(Ab + row * 8192 + kn + ch * 8, &AS[cur ^ 1][(wid * 4 + j) * 512]);
            }
            breg0 = *(const float4*)(Bb + brow * 8192 + kn + bc8 * 4);
            breg1 = *(const float4*)(Bb + (brow + 32) * 8192 + kn + bc8 * 4);
        }

        int l15 = lane & 15, kc = lane >> 4;
        bf16x8 af[4], bfr[4];
        #pragma unroll
        for (int mf = 0; mf < 4; ++mf) {
            int row = wid * 64 + mf * 16 + l15;
            int ch = kc ^ ((row >> 1) & 3);
            af[mf] = *reinterpret_cast<const bf16x8*>(&AS[cur][row * 32 + ch * 8]);
        }
        #pragma unroll
        for (int nf = 0; nf < 4; ++nf) {
            int row = nf * 16 + l15;
            int ch = kc ^ ((row >> 1) & 3);
            bfr[nf] = *reinterpret_cast<const bf16x8*>(&BS[cur][row * 32 + ch * 8]);
        }
        #pragma unroll
        for (int mf = 0; mf < 4; ++mf)
            #pragma unroll
            for (int nf = 0; nf < 4; ++nf)
                acc[mf][nf] = __builtin_amdgcn_mfma_f32_16x16x32_bf16(
                    af[mf], bfr[nf], acc[mf][nf], 0, 0, 0);
        __syncthreads();
    }

    float* P = ks ? P1 : P0;
    float* Cb = P + (b * 256) * 4096 + n0;
    #pragma unroll
    for (int mf = 0; mf < 4; ++mf) {
        int rbase = wid * 64 + mf * 16 + (lane >> 4) * 4;
        #pragma unroll
        for (int nf = 0; nf < 4; ++nf) {
            int col = nf * 16 + (lane & 15);
            #pragma unroll
            for (int r = 0; r < 4; ++r)
                Cb[(rbase + r) * 4096 + col] = acc[mf][nf][r];
        }
    }
}

// ---------------- add2 + transpose: rgrid f32 (c,p) and rgrid_bf bf16 (p,c) ----------------
__global__ __launch_bounds__(256) void add2_t_kernel(
    const float* __restrict__ a, const float* __restrict__ b2,
    float* __restrict__ of32, unsigned short* __restrict__ obf)
{
    __shared__ float tl[64][65];
    int t = threadIdx.x;
    int b = blockIdx.z;
    int c0 = blockIdx.y * 64, p0 = blockIdx.x * 64;
    #pragma unroll
    for (int u = 0; u < 16; ++u) {
        int idx = u * 256 + t;
        int cl = idx >> 6, pl = idx & 63;
        long g = (long)(b * 256 + c0 + cl) * 4096 + p0 + pl;
        float v = a[g] + b2[g];
        tl[cl][pl] = v;
        of32[g] = v;
    }
    __syncthreads();
    #pragma unroll
    for (int u = 0; u < 16; ++u) {
        int idx = u * 256 + t;
        int pl = idx >> 6, cl = idx & 63;
        obf[(long)(b * 4096 + p0 + pl) * 256 + c0 + cl] = f2bf(tl[cl][pl]);
    }
}

// ---------------- weight pack for convT: wp[par][tap][o][c] bf16 ----------------
__global__ __launch_bounds__(256) void wpack_kernel(
    const float* __restrict__ w, unsigned short* __restrict__ wp, int Cout, int Cin)
{
    int id = blockIdx.x * 256 + threadIdx.x;
    int nc8 = Cin >> 3;
    int cch = id % nc8;
    int rest = id / nc8;
    int o = rest % Cout;
    int pt = rest / Cout;                 // 0..15
    if (pt >= 16) return;
    int par = pt >> 2, tap = pt & 3;
    int py = par >> 1, px = par & 1, u = tap >> 1, v = tap & 1;
    int tf = (3 - py - 2 * u) * 4 + (3 - px - 2 * v);
    u16x8 h;
    #pragma unroll
    for (int e = 0; e < 8; ++e)
        h[e] = f2bf(w[((cch * 8 + e) * Cout + o) * 16 + tf]);
    *reinterpret_cast<u16x8*>(&wp[((pt * Cout + o) * Cin) + cch * 8]) = h;
}

// ---------------- generic 1x1 conv via MFMA ----------------
// x bf16 pixel-major [b][P][Cin]; w f32 [Cout][Cin]. Block: M=64, N=256 (4 waves x 64).
// grid (P/256, Cout/64, B). act: 0 none, 1 relu, 2 gelu.
__global__ __launch_bounds__(256) void conv1x1_mfma(
    const unsigned short* __restrict__ xbf, const float* __restrict__ w,
    const float* __restrict__ bias, float* __restrict__ of32,
    unsigned short* __restrict__ obf, int Cin, int Cout, int P, int act)
{
    __shared__ __align__(16) unsigned short XS[2][256 * 32];
    __shared__ __align__(16) unsigned short WS[2][64 * 32];
    int t = threadIdx.x;
    int wid = t >> 6, lane = t & 63;
    int b = blockIdx.z;
    int p0 = blockIdx.x * 256, o0 = blockIdx.y * 64;
    const unsigned short* xb = xbf + (long)b * P * Cin;
    int wm = t >> 2, wq = t & 3;
    int chunks = Cin >> 5;

    f32x4 acc[4][4] = {};

    #pragma unroll
    for (int j = 0; j < 4; ++j) {
        int d16 = (wid * 4 + j) * 64 + lane;
        int p = d16 >> 2;
        int ch = (d16 & 3) ^ ((p >> 1) & 3);
        gload_lds16(xb + (long)(p0 + p) * Cin + ch * 8, &XS[0][(wid * 4 + j) * 512]);
    }
    float4 wr0 = *(const float4*)(w + (o0 + wm) * Cin + wq * 8);
    float4 wr1 = *(const float4*)(w + (o0 + wm) * Cin + wq * 8 + 4);
    __syncthreads();

    for (int cc = 0; cc < chunks; ++cc) {
        int cur = cc & 1;
        {
            int chq = wq ^ ((wm >> 1) & 3);
            u16x8 h;
            h[0] = f2bf(wr0.x); h[1] = f2bf(wr0.y); h[2] = f2bf(wr0.z); h[3] = f2bf(wr0.w);
            h[4] = f2bf(wr1.x); h[5] = f2bf(wr1.y); h[6] = f2bf(wr1.z); h[7] = f2bf(wr1.w);
            *reinterpret_cast<u16x8*>(&WS[cur][wm * 32 + chq * 8]) = h;
        }
        __syncthreads();

        if (cc < chunks - 1) {
            int kn = (cc + 1) * 32;
            #pragma unroll
            for (int j = 0; j < 4; ++j) {
                int d16 = (wid * 4 + j) * 64 + lane;
                int p = d16 >> 2;
                int ch = (d16 & 3) ^ ((p >> 1) & 3);
                gload_lds16(xb + (long)(p0 + p) * Cin + kn + ch * 8,
                            &XS[cur ^ 1][(wid * 4 + j) * 512]);
            }
            wr0 = *(const float4*)(w + (o0 + wm) * Cin + kn + wq * 8);
            wr1 = *(const float4*)(w + (o0 + wm) * Cin + kn + wq * 8 + 4);
        }

        int l15 = lane & 15, kc = lane >> 4;
        bf16x8 af[4], bfr[4];
        #pragma unroll
        for (int mf = 0; mf < 4; ++mf) {
            int row = mf * 16 + l15;
            int ch = kc ^ ((row >> 1) & 3);
            af[mf] = *reinterpret_cast<const bf16x8*>(&WS[cur][row * 32 + ch * 8]);
        }
        #pragma unroll
        for (int nf = 0; nf < 4; ++nf) {
            int row = wid * 64 + nf * 16 + l15;
            int ch = kc ^ ((row >> 1) & 3);
            bfr[nf] = *reinterpret_cast<const bf16x8*>(&XS[cur][row * 32 + ch * 8]);
        }
        #pragma unroll
        for (int mf = 0; mf < 4; ++mf)
            #pragma unroll
            for (int nf = 0; nf < 4; ++nf)
                acc[mf][nf] = __builtin_amdgcn_mfma_f32_16x16x32_bf16(
                    af[mf], bfr[nf], acc[mf][nf], 0, 0, 0);
        __syncthreads();
    }

    int l15 = lane & 15, kc4 = lane >> 4;
    #pragma unroll
    for (int mf = 0; mf < 4; ++mf) {
        #pragma unroll
        for (int nf = 0; nf < 4; ++nf) {
            int p = wid * 64 + nf * 16 + l15;
            ushort4 hb;
            #pragma unroll
            for (int r = 0; r < 4; ++r) {
                int m = mf * 16 + kc4 * 4 + r;
                float v = acc[mf][nf][r] + bias[o0 + m];
                if (act == 1) v = fmaxf(v, 0.f);
                else if (act == 2) v = 0.5f * v * (1.f + erff(v * 0.70710678118f));
                if (of32) of32[((long)(b * Cout) + o0 + m) * P + p0 + p] = v;
                ((unsigned short*)&hb)[r] = f2bf(v);
            }
            if (obf)
                *reinterpret_cast<ushort4*>(
                    &obf[(long)(b * P + p0 + p) * Cout + o0 + mf * 16 + kc4 * 4]) = hb;
        }
    }
}

// ---------------- ConvTranspose2d(k=4,s=2,p=1) via MFMA parity decomposition ----------------
// x bf16 pixel-major [b][Hin*Win][Cin]; wp bf16 [par][tap][Cout][Cin].
// Block: M=64 couts, N = TR*Win parity-pixels (=128), 4 waves x 32 px.
// grid (Hin/TR, Cout/64, B*4). cshift = log2(Win).
__global__ __launch_bounds__(256) void convt_mfma(
    const unsigned short* __restrict__ xbf, const unsigned short* __restrict__ wp,
    const float* __restrict__ bias, const float* __restrict__ g,
    const float* __restrict__ be, const float* __restrict__ mu,
    const float* __restrict__ va, const float* __restrict__ res,
    float* __restrict__ of32, unsigned short* __restrict__ obf,
    int Cin, int Cout, int Hin, int Win, int TR, int cshift, int OCtot, int cof)
{
    __shared__ __align__(16) unsigned short XS[165 * 32];
    __shared__ __align__(16) unsigned short WS[4 * 64 * 32];
    int t = threadIdx.x;
    int wid = t >> 6, lane = t & 63;
    int z = blockIdx.z;
    int b = z >> 2, par = z & 3;
    int py = par >> 1, px = par & 1;
    int o0 = blockIdx.y * 64;
    int i0 = blockIdx.x * TR;
    int CW = Win, CW1 = CW + 1;
    int npatch = (TR + 1) * CW1;
    int Pin = Hin * Win, Pout = 4 * Hin * Win;
    const unsigned short* xb = xbf + (long)b * Pin * Cin;
    int chunks = Cin >> 5;
    int l15 = lane & 15, kc = lane >> 4;

    f32x4 acc[4][2] = {};

    for (int cc = 0; cc < chunks; ++cc) {
        __syncthreads();
        // stage input patch (with halo, zero-filled OOB)
        for (int idx = t; idx < npatch * 4; idx += 256) {
            int pp = idx >> 2, ql = idx & 3;
            int qs = ql ^ ((pp >> 1) & 3);
            int a = pp / CW1, bcol = pp - a * CW1;
            int iy = i0 - (1 - py) + a;
            int ix = bcol - (1 - px);
            u16x8 v = {};
            if (iy >= 0 && iy < Hin && ix >= 0 && ix < Win)
                v = *reinterpret_cast<const u16x8*>(
                    &xb[(long)(iy * Win + ix) * Cin + cc * 32 + qs * 8]);
            *reinterpret_cast<u16x8*>(&XS[pp * 32 + ql * 8]) = v;
        }
        // stage 4 tap weight tiles
        {
            int m = t >> 2, q = t & 3;
            int chq = q ^ ((m >> 1) & 3);
            #pragma unroll
            for (int tap = 0; tap < 4; ++tap) {
                u16x8 v = *reinterpret_cast<const u16x8*>(
                    &wp[((long)((par * 4 + tap) * Cout + o0 + m)) * Cin + cc * 32 + q * 8]);
                *reinterpret_cast<u16x8*>(&WS[tap * 2048 + m * 32 + chq * 8]) = v;
            }
        }
        __syncthreads();

        #pragma unroll
        for (int tap = 0; tap < 4; ++tap) {
            int u = tap >> 1, v = tap & 1;
            bf16x8 af[4], bfr[2];
            #pragma unroll
            for (int mf = 0; mf < 4; ++mf) {
                int row = mf * 16 + l15;
                int ch = kc ^ ((row >> 1) & 3);
                af[mf] = *reinterpret_cast<const bf16x8*>(&WS[tap * 2048 + row * 32 + ch * 8]);
            }
            #pragma unroll
            for (int nf = 0; nf < 2; ++nf) {
                int n = wid * 32 + nf * 16 + l15;
                int rn = n >> cshift, cn = n & (CW - 1);
                int pp = (rn + u) * CW1 + cn + v;
                int ch = kc ^ ((pp >> 1) & 3);
                bfr[nf] = *reinterpret_cast<const bf16x8*>(&XS[pp * 32 + ch * 8]);
            }
            #pragma unroll
            for (int mf = 0; mf < 4; ++mf)
                #pragma unroll
                for (int nf = 0; nf < 2; ++nf)
                    acc[mf][nf] = __builtin_amdgcn_mfma_f32_16x16x32_bf16(
                        af[mf], bfr[nf], acc[mf][nf], 0, 0, 0);
        }
    }

    int kc4 = lane >> 4;
    #pragma unroll
    for (int nf = 0; nf < 2; ++nf) {
        int n = wid * 32 + nf * 16 + l15;
        int rn = n >> cshift, cn = n & (CW - 1);
        int y = 2 * (i0 + rn) + py;
        int xx = 2 * cn + px;
        int pout = y * 2 * Win + xx;
        #pragma unroll
        for (int mf = 0; mf < 4; ++mf) {
            ushort4 hb;
            #pragma unroll
            for (int r = 0; r < 4; ++r) {
                int m = mf * 16 + kc4 * 4 + r;
                int o = o0 + m;
                float s = g[o] * rsqrtf(va[o] + EPSV);
                float v = (acc[mf][nf][r] + bias[o]) * s + (be[o] - mu[o] * s);
                if (res) v += res[((long)(b * Cout) + o) * Pout + pout];
                if (of32) of32[((long)(b * Cout) + o) * Pout + pout] = v;
                ((unsigned short*)&hb)[r] = f2bf(v);
            }
            if (obf)
                *reinterpret_cast<ushort4*>(
                    &obf[(long)(b * Pout + pout) * OCtot + cof + o0 + mf * 16 + kc4 * 4]) = hb;
        }
    }
}

// ---------------- fused lift_net + lifting add (f32, optional bf16 concat write) ----------------
__global__ __launch_bounds__(256) void lift_net_kernel(
    const float* __restrict__ xin, int x_sB, int x_sC, int x_sR, int x_sA,
    const float* __restrict__ oth, int o_sB, int o_sC, int o_sR, int o_sA,
    float* __restrict__ outp, int u_sB, int u_sC, int u_sR, int u_sA,
    const float* __restrict__ w1, const float* __restrict__ b1,
    const float* __restrict__ w2, const float* __restrict__ b2,
    int R, int L, float sign,
    unsigned short* __restrict__ obf, int Pb, int OCb, int cofb)
{
    __shared__ float xsm[4864];
    __shared__ float hsm[8192];
    __shared__ float ws1[4096];
    __shared__ float w2s[8192];
    int t = threadIdx.x;
    int b = blockIdx.z;
    int rpb = 64 / L;
    int row0 = blockIdx.x * rpb;
    int Lp = L + 3;
    int total = 64 * rpb * Lp;
    for (int idx = t; idx < total; idx += 256) {
        int c = idx / (rpb * Lp);
        int rem = idx - c * rpb * Lp;
        int rr_l = rem / Lp;
        int q = rem - rr_l * Lp;
        int s = q - 2;
        s = (s < 0) ? -s : s;
        if (s >= L) s = 2 * L - 2 - s;
        xsm[idx] = xin[b * x_sB + c * x_sC + (row0 + rr_l) * x_sR + s * x_sA];
    }
    for (int idx = t; idx < 8192; idx += 256) w2s[idx] = w2[idx];

    int g = t & 63, ocg = t >> 6;
    int rl = g / L, jl = g - rl * L;
    float acc1[32] = {};
    for (int cc = 0; cc < 8; cc++) {
        __syncthreads();
        #pragma unroll
        for (int u = 0; u < 16; u++) {
            int idx = t + u * 256;
            int oc = idx >> 5, r = idx & 31;
            ws1[idx] = w1[oc * 256 + cc * 32 + r];
        }
        __syncthreads();
        #pragma unroll
        for (int c8 = 0; c8 < 8; c8++) {
            int c = cc * 8 + c8;
            const float* xr = &xsm[(c * rpb + rl) * Lp + jl];
            float x0 = xr[0], x1 = xr[1], x2 = xr[2], x3 = xr[3];
            #pragma unroll
            for (int k = 0; k < 32; k++) {
                const float* wr = &ws1[(ocg * 32 + k) * 32 + c8 * 4];
                acc1[k] += wr[0] * x0 + wr[1] * x1 + wr[2] * x2 + wr[3] * x3;
            }
        }
    }
    #pragma unroll
    for (int k = 0; k < 32; k++) {
        int oc = ocg * 32 + k;
        hsm[oc * 64 + g] = fmaxf(acc1[k] + b1[oc], 0.f);
    }
    __syncthreads();
    float acc2[16] = {};
    #pragma unroll 4
    for (int h = 0; h < 128; h++) {
        float hv = hsm[h * 64 + g];
        #pragma unroll
        for (int kk = 0; kk < 16; kk++)
            acc2[kk] += w2s[(ocg * 16 + kk) * 128 + h] * hv;
    }
    int rg = row0 + rl;
    int p = rg * u_sR + jl * u_sA;   // pixel index (u_s* are pixel strides)
    #pragma unroll
    for (int kk = 0; kk < 16; kk++) {
        int o = ocg * 16 + kk;
        float v = oth[b * o_sB + o * o_sC + rg * o_sR + jl * o_sA]
                + sign * tanhf(acc2[kk] + b2[o]);
        outp[b * u_sB + o * u_sC + p] = v;
        if (obf) obf[(long)(b * Pb + p) * OCb + cofb + o] = f2bf(v);
    }
}

// ---------------- depthwise 3x3 ----------------
__global__ __launch_bounds__(256) void dw3x3_kernel(
    const float* __restrict__ x, const float* __restrict__ w, const float* __restrict__ bias,
    const float* __restrict__ scale, float* __restrict__ out, int relu_out)
{
    int c = blockIdx.y, b = blockIdx.z;
    int pix = blockIdx.x * 256 + threadIdx.x;
    int y = pix >> 6, xc = pix & 63;
    const float* xp = x + (b * 256 + c) * 4096;
    const float* wc = w + c * 9;
    float acc = bias[c];
    #pragma unroll
    for (int ky = 0; ky < 3; ky++) {
        int yy = y + ky - 1;
        if (yy < 0 || yy > 63) continue;
        #pragma unroll
        for (int kx = 0; kx < 3; kx++) {
            int xx = xc + kx - 1;
            if (xx < 0 || xx > 63) continue;
            acc += wc[ky * 3 + kx] * xp[yy * 64 + xx];
        }
    }
    if (relu_out) acc = fmaxf(acc, 0.f);
    if (scale) acc *= scale[c];
    out[(b * 256 + c) * 4096 + pix] = acc;
}

// ---------------- final gather + residual ----------------
__global__ __launch_bounds__(256) void gather_add_kernel(
    const float* __restrict__ tok, const int* __restrict__ idx,
    const float* __restrict__ t2, float* __restrict__ out)
{
    int i = blockIdx.x * 256 + threadIdx.x;
    int bc = i >> 13;
    out[i] = tok[i] + t2[(bc << 12) + idx[i]];
}

extern "C" void kernel_launch(void* const* d_in, const int* in_sizes, int n_in,
                              void* d_out, int out_size, void* d_ws, size_t ws_size,
                              hipStream_t stream)
{
    const float* tokens = (const float*)d_in[0];
    const float* fm     = (const float*)d_in[1];
    const int*   infl   = (const int*)d_in[2];
    const float* bng = (const float*)d_in[3];
    const float* bnb = (const float*)d_in[4];
    const float* bnm = (const float*)d_in[5];
    const float* bnv = (const float*)d_in[6];
    const float* red_w = (const float*)d_in[7];
    const float* red_b = (const float*)d_in[8];
    const float* lw1 = (const float*)d_in[9];
    const float* lb1 = (const float*)d_in[10];
    const float* lw2 = (const float*)d_in[11];
    const float* lb2 = (const float*)d_in[12];
    const float* f2w1 = (const float*)d_in[13];
    const float* f2b1 = (const float*)d_in[14];
    const float* f2w2 = (const float*)d_in[15];
    const float* f2b2 = (const float*)d_in[16];
    const float* ct2w = (const float*)d_in[17];
    const float* ct2b = (const float*)d_in[18];
    const float* bn2g = (const float*)d_in[19];
    const float* bn2b = (const float*)d_in[20];
    const float* bn2m = (const float*)d_in[21];
    const float* bn2v = (const float*)d_in[22];
    const float* f1w1 = (const float*)d_in[23];
    const float* f1b1 = (const float*)d_in[24];
    const float* f1w2 = (const float*)d_in[25];
    const float* f1b2 = (const float*)d_in[26];
    const float* ct1w = (const float*)d_in[27];
    const float* ct1b = (const float*)d_in[28];
    const float* bn1g = (const float*)d_in[29];
    const float* bn1b = (const float*)d_in[30];
    const float* bn1m = (const float*)d_in[31];
    const float* bn1v = (const float*)d_in[32];
    const float* dw1w = (const float*)d_in[33];
    const float* dw1b = (const float*)d_in[34];
    const float* dw2w = (const float*)d_in[35];
    const float* dw2b = (const float*)d_in[36];
    const float* scw  = (const float*)d_in[37];

    float* ws = (float*)d_ws;
    // layout (float slots), total 11,337,728 = 45.35 MB
    unsigned short* Abf = (unsigned short*)ws;              // [0, 2,097,152) fl
    float* rgrid = ws + 0;                                  // overlaps Abf (dead after flatten)
    float* p0    = ws + 2097152;
    float* p1    = ws + 4194304;
    unsigned short* rgrid_bf = (unsigned short*)(ws + 6291456);  // 1,048,576 fl
    float* rr    = ws + 7340032;    // 524,288
    float* c1    = ws + 7864320;    // 262,144
    float* d1    = ws + 8126464;    // 262,144
    float* c2    = ws + 8388608;    // 65,536
    float* d2    = ws + 8454144;    // 65,536
    float* x2    = ws + 8519680;    // 131,072
    unsigned short* x2_bf  = (unsigned short*)(ws + 8650752);   // 65,536 fl
    float* x1    = ws + 8716288;    // 786,432
    unsigned short* x1_bf  = (unsigned short*)(ws + 9502720);   // 393,216 fl
    unsigned short* g2_bf  = (unsigned short*)(ws + 9895936);   // 65,536 fl
    unsigned short* y2p_bf = (unsigned short*)(ws + 9961472);   // 65,536 fl
    unsigned short* g1_bf  = (unsigned short*)(ws + 10027008);  // 262,144 fl
    unsigned short* y1p_bf = (unsigned short*)(ws + 10289152);  // 262,144 fl
    unsigned short* wp2    = (unsigned short*)(ws + 10551296);  // 262,144 fl
    unsigned short* wp1    = (unsigned short*)(ws + 10813440);  // 524,288 fl
    float* r2 = p0;
    float* t1 = p1;
    float* t2 = rgrid;

    // weight packs (independent)
    wpack_kernel<<<512, 256, 0, stream>>>(ct1w, wp1, 256, 256);
    wpack_kernel<<<256, 256, 0, stream>>>(ct2w, wp2, 128, 256);

    // 1. BN -> bf16
    bn_to_bf16_kernel<<<4096, 256, 0, stream>>>((const float4*)tokens, (ushort4*)Abf,
                                                bng, bnb, bnm, bnv);
    // 2. flatten einsum (MFMA, K-split 2) + reduce/transpose
    flatten_gemm_mfma<<<dim3(64, 1, 4), 256, 0, stream>>>(Abf, fm, p0, p1);
    add2_t_kernel<<<dim3(64, 4, 2), 256, 0, stream>>>(p0, p1, rgrid, rgrid_bf);
    // 3. reduce 1x1 (256->64), f32 out
    conv1x1_mfma<<<dim3(16, 1, 2), 256, 0, stream>>>(rgrid_bf, red_w, red_b,
                                                     rr, (unsigned short*)nullptr,
                                                     256, 64, 4096, 0);

    auto lift = [&](const float* xin, int xsB, int xsC, int xsR, int xsA,
                    const float* ot, int osB, int osC, int osR, int osA,
                    float* op, int usB, int usC, int usR, int usA,
                    int lvl, int sch, int net, int R, int L, float sign,
                    unsigned short* obf, int Pb, int OCb, int cofb) {
        int widx = (lvl * 2 + sch) * 2 + net;
        lift_net_kernel<<<dim3(R * L / 64, 1, 2), 256, 0, stream>>>(
            xin, xsB, xsC, xsR, xsA, ot, osB, osC, osR, osA, op, usB, usC, usR, usA,
            lw1 + widx * 32768, lb1 + widx * 128, lw2 + widx * 8192, lb2 + widx * 64,
            R, L, sign, obf, Pb, OCb, cofb);
    };

    // ---- level 1, horizontal (rr: B,64,64,64) ----
    lift(rr,     262144, 4096, 64, 2,  rr + 1, 262144, 4096, 64, 2,
         d1,     131072, 2048, 32, 1,  0, 0, 0, 64, 32, -1.f, nullptr, 0, 0, 0);
    lift(d1,     131072, 2048, 32, 1,  rr,     262144, 4096, 64, 2,
         c1,     131072, 2048, 32, 1,  0, 0, 1, 64, 32, +1.f, nullptr, 0, 0, 0);
    // ---- level 1, vertical on c1 -> LH1 (x1 ch64), LL1 (x1 ch0) ----
    lift(c1,      131072, 2048, 1, 64,  c1 + 32, 131072, 2048, 1, 64,
         x1 + 65536, 393216, 1024, 1, 32,  0, 1, 0, 32, 32, -1.f, x1_bf, 1024, 384, 64);
    lift(x1 + 65536, 393216, 1024, 1, 32,  c1, 131072, 2048, 1, 64,
         x1 + 0,     393216, 1024, 1, 32,  0, 1, 1, 32, 32, +1.f, x1_bf, 1024, 384, 0);
    // ---- level 1, vertical on d1 -> HH1 (ch192), HL1 (ch128) ----
    lift(d1,      131072, 2048, 1, 64,  d1 + 32, 131072, 2048, 1, 64,
         x1 + 196608, 393216, 1024, 1, 32,  0, 1, 0, 32, 32, -1.f, x1_bf, 1024, 384, 192);
    lift(x1 + 196608, 393216, 1024, 1, 32,  d1, 131072, 2048, 1, 64,
         x1 + 131072, 393216, 1024, 1, 32,  0, 1, 1, 32, 32, +1.f, x1_bf, 1024, 384, 128);
    // ---- level 2, horizontal on LL1 ----
    lift(x1,     393216, 1024, 32, 2,  x1 + 1, 393216, 1024, 32, 2,
         d2,     65536, 512, 16, 1,   1, 0, 0, 32, 16, -1.f, nullptr, 0, 0, 0);
    lift(d2,     65536, 512, 16, 1,   x1,     393216, 1024, 32, 2,
         c2,     65536, 512, 16, 1,   1, 0, 1, 32, 16, +1.f, nullptr, 0, 0, 0);
    // ---- level 2, vertical on c2 -> LH2 (x2 ch64), LL2 (ch0) ----
    lift(c2,      65536, 512, 1, 32,  c2 + 16, 65536, 512, 1, 32,
         x2 + 16384, 65536, 256, 1, 16,  1, 1, 0, 16, 16, -1.f, x2_bf, 256, 256, 64);
    lift(x2 + 16384, 65536, 256, 1, 16,  c2, 65536, 512, 1, 32,
         x2 + 0,     65536, 256, 1, 16,  1, 1, 1, 16, 16, +1.f, x2_bf, 256, 256, 0);
    // ---- level 2, vertical on d2 -> HH2 (ch192), HL2 (ch128) ----
    lift(d2,      65536, 512, 1, 32,  d2 + 16, 65536, 512, 1, 32,
         x2 + 49152, 65536, 256, 1, 16,  1, 1, 0, 16, 16, -1.f, x2_bf, 256, 256, 192);
    lift(x2 + 49152, 65536, 256, 1, 16,  d2, 65536, 512, 1, 32,
         x2 + 32768, 65536, 256, 1, 16,  1, 1, 1, 16, 16, +1.f, x2_bf, 256, 256, 128);

    // ---- ff2 (bf16 chain) + ct2 -> x1_bf ch 256..383 ----
    conv1x1_mfma<<<dim3(1, 4, 2), 256, 0, stream>>>(x2_bf, f2w1, f2b1,
        (float*)nullptr, g2_bf, 256, 256, 256, 2);
    conv1x1_mfma<<<dim3(1, 4, 2), 256, 0, stream>>>(g2_bf, f2w2, f2b2,
        (float*)nullptr, y2p_bf, 256, 256, 256, 0);
    convt_mfma<<<dim3(2, 2, 8), 256, 0, stream>>>(y2p_bf, wp2, ct2b,
        bn2g, bn2b, bn2m, bn2v, (const float*)nullptr,
        (float*)nullptr, x1_bf, 256, 128, 16, 16, 8, 4, 384, 256);

    // ---- ff1 + ct1 (+res rgrid) -> r2 f32 ----
    conv1x1_mfma<<<dim3(4, 4, 2), 256, 0, stream>>>(x1_bf, f1w1, f1b1,
        (float*)nullptr, g1_bf, 384, 256, 1024, 2);
    conv1x1_mfma<<<dim3(4, 4, 2), 256, 0, stream>>>(g1_bf, f1w2, f1b2,
        (float*)nullptr, y1p_bf, 256, 256, 1024, 0);
    convt_mfma<<<dim3(8, 4, 8), 256, 0, stream>>>(y1p_bf, wp1, ct1b,
        bn1g, bn1b, bn1m, bn1v, rgrid,
        r2, (unsigned short*)nullptr, 256, 256, 32, 32, 4, 5, 0, 0);

    // ---- depthwise convs + scale ----
    dw3x3_kernel<<<dim3(16, 256, 2), 256, 0, stream>>>(r2, dw1w, dw1b,
        (const float*)nullptr, t1, 1);
    dw3x3_kernel<<<dim3(16, 256, 2), 256, 0, stream>>>(t1, dw2w, dw2b, scw, t2, 0);

    // ---- inflate gather + residual ----
    gather_add_kernel<<<16384, 256, 0, stream>>>(tokens, infl, t2, (float*)d_out);
}

// Round 4
// 753.125 us; speedup vs baseline: 3.2662x; 1.8561x over previous
//
#include <hip/hip_runtime.h>
#include <math.h>

#define EPSV 1e-5f

typedef __attribute__((ext_vector_type(8))) short bf16x8;
typedef __attribute__((ext_vector_type(4))) float f32x4;
typedef __attribute__((ext_vector_type(8))) unsigned short u16x8;

__device__ inline unsigned short f2bf(float f) {
    unsigned u = __float_as_uint(f);
    unsigned r = (u + 0x7fffu + ((u >> 16) & 1u)) >> 16;
    return (unsigned short)r;
}

__device__ inline void gload_lds16(const void* g, void* l) {
    __builtin_amdgcn_global_load_lds(
        (const __attribute__((address_space(1))) void*)g,
        (__attribute__((address_space(3))) void*)l, 16, 0, 0);
}

// ---------------- BN over tokens (B,C,N) -> bf16 ----------------
__global__ __launch_bounds__(256) void bn_to_bf16_kernel(
    const float4* __restrict__ x, ushort4* __restrict__ y,
    const float* __restrict__ g, const float* __restrict__ be,
    const float* __restrict__ mu, const float* __restrict__ va)
{
    int i = blockIdx.x * 256 + threadIdx.x;
    int c = (i >> 11) & 255;
    float s = g[c] * rsqrtf(va[c] + EPSV);
    float t = be[c] - mu[c] * s;
    float4 v = x[i];
    ushort4 h;
    h.x = f2bf(v.x * s + t); h.y = f2bf(v.y * s + t);
    h.z = f2bf(v.z * s + t); h.w = f2bf(v.w * s + t);
    y[i] = h;
}

// ---------------- MFMA flatten einsum, K-split 4 ----------------
// grid (64, 1, 8): z = b*4 + ks. Each block: BM=256 c, BN=64 m, K-range 2048.
__global__ __launch_bounds__(256) void flatten_gemm_mfma(
    const unsigned short* __restrict__ A, const float* __restrict__ Bm,
    float* __restrict__ Pbase)
{
    __shared__ __align__(16) unsigned short AS[2][256 * 32];
    __shared__ __align__(16) unsigned short BS[2][64 * 32];
    int t = threadIdx.x;
    int wid = t >> 6, lane = t & 63;
    int n0 = blockIdx.x * 64;
    int ks = blockIdx.z & 3, b = blockIdx.z >> 2;
    const unsigned short* Ab = A + b * (256 * 8192);
    const float* Bb = Bm + (long)b * (4096 * 8192) + (long)n0 * 8192;
    int k0 = ks * 2048;
    int brow = t >> 3, bc8 = t & 7;

    f32x4 acc[4][4] = {};

    #pragma unroll
    for (int j = 0; j < 4; ++j) {
        int d16 = (wid * 4 + j) * 64 + lane;
        int row = d16 >> 2;
        int ch = (d16 & 3) ^ ((row >> 1) & 3);
        gload_lds16(Ab + row * 8192 + k0 + ch * 8, &AS[0][(wid * 4 + j) * 512]);
    }
    float4 breg0 = *(const float4*)(Bb + brow * 8192 + k0 + bc8 * 4);
    float4 breg1 = *(const float4*)(Bb + (brow + 32) * 8192 + k0 + bc8 * 4);
    __syncthreads();

    for (int it = 0; it < 64; ++it) {
        int cur = it & 1;
        {
            int ch16 = (bc8 >> 1) ^ ((brow >> 1) & 3);
            ushort4 h;
            h.x = f2bf(breg0.x); h.y = f2bf(breg0.y); h.z = f2bf(breg0.z); h.w = f2bf(breg0.w);
            *reinterpret_cast<ushort4*>(&BS[cur][brow * 32 + ch16 * 8 + (bc8 & 1) * 4]) = h;
            int r2 = brow + 32;
            int ch16b = (bc8 >> 1) ^ ((r2 >> 1) & 3);
            ushort4 h2;
            h2.x = f2bf(breg1.x); h2.y = f2bf(breg1.y); h2.z = f2bf(breg1.z); h2.w = f2bf(breg1.w);
            *reinterpret_cast<ushort4*>(&BS[cur][r2 * 32 + ch16b * 8 + (bc8 & 1) * 4]) = h2;
        }
        __syncthreads();

        if (it < 63) {
            int kn = k0 + (it + 1) * 32;
            #pragma unroll
            for (int j = 0; j < 4; ++j) {
                int d16 = (wid * 4 + j) * 64 + lane;
                int row = d16 >> 2;
                int ch = (d16 & 3) ^ ((row >> 1) & 3);
                gload_lds16(Ab + row * 8192 + kn + ch * 8, &AS[cur ^ 1][(wid * 4 + j) * 512]);
            }
            breg0 = *(const float4*)(Bb + brow * 8192 + kn + bc8 * 4);
            breg1 = *(const float4*)(Bb + (brow + 32) * 8192 + kn + bc8 * 4);
        }

        int l15 = lane & 15, kc = lane >> 4;
        bf16x8 af[4], bfr[4];
        #pragma unroll
        for (int mf = 0; mf < 4; ++mf) {
            int row = wid * 64 + mf * 16 + l15;
            int ch = kc ^ ((row >> 1) & 3);
            af[mf] = *reinterpret_cast<const bf16x8*>(&AS[cur][row * 32 + ch * 8]);
        }
        #pragma unroll
        for (int nf = 0; nf < 4; ++nf) {
            int row = nf * 16 + l15;
            int ch = kc ^ ((row >> 1) & 3);
            bfr[nf] = *reinterpret_cast<const bf16x8*>(&BS[cur][row * 32 + ch * 8]);
        }
        #pragma unroll
        for (int mf = 0; mf < 4; ++mf)
            #pragma unroll
            for (int nf = 0; nf < 4; ++nf)
                acc[mf][nf] = __builtin_amdgcn_mfma_f32_16x16x32_bf16(
                    af[mf], bfr[nf], acc[mf][nf], 0, 0, 0);
        __syncthreads();
    }

    float* P = Pbase + ks * 2097152;
    float* Cb = P + (b * 256) * 4096 + n0;
    #pragma unroll
    for (int mf = 0; mf < 4; ++mf) {
        int rbase = wid * 64 + mf * 16 + (lane >> 4) * 4;
        #pragma unroll
        for (int nf = 0; nf < 4; ++nf) {
            int col = nf * 16 + (lane & 15);
            #pragma unroll
            for (int r = 0; r < 4; ++r)
                Cb[(rbase + r) * 4096 + col] = acc[mf][nf][r];
        }
    }
}

// ---------------- add4 + transpose: rgrid f32 (c,p) and rgrid_bf bf16 (p,c) ----------------
__global__ __launch_bounds__(256) void add4_t_kernel(
    const float* __restrict__ p, float* __restrict__ of32, unsigned short* __restrict__ obf)
{
    __shared__ float tl[64][65];
    int t = threadIdx.x;
    int b = blockIdx.z;
    int c0 = blockIdx.y * 64, p0 = blockIdx.x * 64;
    #pragma unroll
    for (int u = 0; u < 16; ++u) {
        int idx = u * 256 + t;
        int cl = idx >> 6, pl = idx & 63;
        long g = (long)(b * 256 + c0 + cl) * 4096 + p0 + pl;
        float v = p[g] + p[g + 2097152] + p[g + 2 * 2097152] + p[g + 3 * 2097152];
        tl[cl][pl] = v;
        of32[g] = v;
    }
    __syncthreads();
    #pragma unroll
    for (int u = 0; u < 16; ++u) {
        int idx = u * 256 + t;
        int pl = idx >> 6, cl = idx & 63;
        obf[(long)(b * 4096 + p0 + pl) * 256 + c0 + cl] = f2bf(tl[cl][pl]);
    }
}

// ---------------- weight pack for convT: wp[par][tap][o][c] bf16 ----------------
__global__ __launch_bounds__(256) void wpack_kernel(
    const float* __restrict__ w, unsigned short* __restrict__ wp, int Cout, int Cin)
{
    int id = blockIdx.x * 256 + threadIdx.x;
    int nc8 = Cin >> 3;
    int cch = id % nc8;
    int rest = id / nc8;
    int o = rest % Cout;
    int pt = rest / Cout;
    if (pt >= 16) return;
    int par = pt >> 2, tap = pt & 3;
    int py = par >> 1, px = par & 1, u = tap >> 1, v = tap & 1;
    int tf = (3 - py - 2 * u) * 4 + (3 - px - 2 * v);
    u16x8 h;
    #pragma unroll
    for (int e = 0; e < 8; ++e)
        h[e] = f2bf(w[((cch * 8 + e) * Cout + o) * 16 + tf]);
    *reinterpret_cast<u16x8*>(&wp[((pt * Cout + o) * Cin) + cch * 8]) = h;
}

// ---------------- generic 1x1 conv via MFMA ----------------
__global__ __launch_bounds__(256) void conv1x1_mfma(
    const unsigned short* __restrict__ xbf, const float* __restrict__ w,
    const float* __restrict__ bias, float* __restrict__ of32,
    unsigned short* __restrict__ obf, int Cin, int Cout, int P, int act)
{
    __shared__ __align__(16) unsigned short XS[2][256 * 32];
    __shared__ __align__(16) unsigned short WS[2][64 * 32];
    int t = threadIdx.x;
    int wid = t >> 6, lane = t & 63;
    int b = blockIdx.z;
    int p0 = blockIdx.x * 256, o0 = blockIdx.y * 64;
    const unsigned short* xb = xbf + (long)b * P * Cin;
    int wm = t >> 2, wq = t & 3;
    int chunks = Cin >> 5;

    f32x4 acc[4][4] = {};

    #pragma unroll
    for (int j = 0; j < 4; ++j) {
        int d16 = (wid * 4 + j) * 64 + lane;
        int p = d16 >> 2;
        int ch = (d16 & 3) ^ ((p >> 1) & 3);
        gload_lds16(xb + (long)(p0 + p) * Cin + ch * 8, &XS[0][(wid * 4 + j) * 512]);
    }
    float4 wr0 = *(const float4*)(w + (o0 + wm) * Cin + wq * 8);
    float4 wr1 = *(const float4*)(w + (o0 + wm) * Cin + wq * 8 + 4);
    __syncthreads();

    for (int cc = 0; cc < chunks; ++cc) {
        int cur = cc & 1;
        {
            int chq = wq ^ ((wm >> 1) & 3);
            u16x8 h;
            h[0] = f2bf(wr0.x); h[1] = f2bf(wr0.y); h[2] = f2bf(wr0.z); h[3] = f2bf(wr0.w);
            h[4] = f2bf(wr1.x); h[5] = f2bf(wr1.y); h[6] = f2bf(wr1.z); h[7] = f2bf(wr1.w);
            *reinterpret_cast<u16x8*>(&WS[cur][wm * 32 + chq * 8]) = h;
        }
        __syncthreads();

        if (cc < chunks - 1) {
            int kn = (cc + 1) * 32;
            #pragma unroll
            for (int j = 0; j < 4; ++j) {
                int d16 = (wid * 4 + j) * 64 + lane;
                int p = d16 >> 2;
                int ch = (d16 & 3) ^ ((p >> 1) & 3);
                gload_lds16(xb + (long)(p0 + p) * Cin + kn + ch * 8,
                            &XS[cur ^ 1][(wid * 4 + j) * 512]);
            }
            wr0 = *(const float4*)(w + (o0 + wm) * Cin + kn + wq * 8);
            wr1 = *(const float4*)(w + (o0 + wm) * Cin + kn + wq * 8 + 4);
        }

        int l15 = lane & 15, kc = lane >> 4;
        bf16x8 af[4], bfr[4];
        #pragma unroll
        for (int mf = 0; mf < 4; ++mf) {
            int row = mf * 16 + l15;
            int ch = kc ^ ((row >> 1) & 3);
            af[mf] = *reinterpret_cast<const bf16x8*>(&WS[cur][row * 32 + ch * 8]);
        }
        #pragma unroll
        for (int nf = 0; nf < 4; ++nf) {
            int row = wid * 64 + nf * 16 + l15;
            int ch = kc ^ ((row >> 1) & 3);
            bfr[nf] = *reinterpret_cast<const bf16x8*>(&XS[cur][row * 32 + ch * 8]);
        }
        #pragma unroll
        for (int mf = 0; mf < 4; ++mf)
            #pragma unroll
            for (int nf = 0; nf < 4; ++nf)
                acc[mf][nf] = __builtin_amdgcn_mfma_f32_16x16x32_bf16(
                    af[mf], bfr[nf], acc[mf][nf], 0, 0, 0);
        __syncthreads();
    }

    int l15 = lane & 15, kc4 = lane >> 4;
    #pragma unroll
    for (int mf = 0; mf < 4; ++mf) {
        #pragma unroll
        for (int nf = 0; nf < 4; ++nf) {
            int p = wid * 64 + nf * 16 + l15;
            ushort4 hb;
            #pragma unroll
            for (int r = 0; r < 4; ++r) {
                int m = mf * 16 + kc4 * 4 + r;
                float v = acc[mf][nf][r] + bias[o0 + m];
                if (act == 1) v = fmaxf(v, 0.f);
                else if (act == 2) v = 0.5f * v * (1.f + erff(v * 0.70710678118f));
                if (of32) of32[((long)(b * Cout) + o0 + m) * P + p0 + p] = v;
                ((unsigned short*)&hb)[r] = f2bf(v);
            }
            if (obf)
                *reinterpret_cast<ushort4*>(
                    &obf[(long)(b * P + p0 + p) * Cout + o0 + mf * 16 + kc4 * 4]) = hb;
        }
    }
}

// ---------------- ConvTranspose2d(k=4,s=2,p=1) via MFMA parity decomposition ----------------
__global__ __launch_bounds__(256) void convt_mfma(
    const unsigned short* __restrict__ xbf, const unsigned short* __restrict__ wp,
    const float* __restrict__ bias, const float* __restrict__ g,
    const float* __restrict__ be, const float* __restrict__ mu,
    const float* __restrict__ va, const float* __restrict__ res,
    float* __restrict__ of32, unsigned short* __restrict__ obf,
    int Cin, int Cout, int Hin, int Win, int TR, int cshift, int OCtot, int cof)
{
    __shared__ __align__(16) unsigned short XS[165 * 32];
    __shared__ __align__(16) unsigned short WS[4 * 64 * 32];
    int t = threadIdx.x;
    int wid = t >> 6, lane = t & 63;
    int z = blockIdx.z;
    int b = z >> 2, par = z & 3;
    int py = par >> 1, px = par & 1;
    int o0 = blockIdx.y * 64;
    int i0 = blockIdx.x * TR;
    int CW = Win, CW1 = CW + 1;
    int npatch = (TR + 1) * CW1;
    int Pin = Hin * Win, Pout = 4 * Hin * Win;
    const unsigned short* xb = xbf + (long)b * Pin * Cin;
    int chunks = Cin >> 5;
    int l15 = lane & 15, kc = lane >> 4;

    f32x4 acc[4][2] = {};

    for (int cc = 0; cc < chunks; ++cc) {
        __syncthreads();
        for (int idx = t; idx < npatch * 4; idx += 256) {
            int pp = idx >> 2, ql = idx & 3;
            int qs = ql ^ ((pp >> 1) & 3);
            int a = pp / CW1, bcol = pp - a * CW1;
            int iy = i0 - (1 - py) + a;
            int ix = bcol - (1 - px);
            u16x8 v = {};
            if (iy >= 0 && iy < Hin && ix >= 0 && ix < Win)
                v = *reinterpret_cast<const u16x8*>(
                    &xb[(long)(iy * Win + ix) * Cin + cc * 32 + qs * 8]);
            *reinterpret_cast<u16x8*>(&XS[pp * 32 + ql * 8]) = v;
        }
        {
            int m = t >> 2, q = t & 3;
            int chq = q ^ ((m >> 1) & 3);
            #pragma unroll
            for (int tap = 0; tap < 4; ++tap) {
                u16x8 v = *reinterpret_cast<const u16x8*>(
                    &wp[((long)((par * 4 + tap) * Cout + o0 + m)) * Cin + cc * 32 + q * 8]);
                *reinterpret_cast<u16x8*>(&WS[tap * 2048 + m * 32 + chq * 8]) = v;
            }
        }
        __syncthreads();

        #pragma unroll
        for (int tap = 0; tap < 4; ++tap) {
            int u = tap >> 1, v = tap & 1;
            bf16x8 af[4], bfr[2];
            #pragma unroll
            for (int mf = 0; mf < 4; ++mf) {
                int row = mf * 16 + l15;
                int ch = kc ^ ((row >> 1) & 3);
                af[mf] = *reinterpret_cast<const bf16x8*>(&WS[tap * 2048 + row * 32 + ch * 8]);
            }
            #pragma unroll
            for (int nf = 0; nf < 2; ++nf) {
                int n = wid * 32 + nf * 16 + l15;
                int rn = n >> cshift, cn = n & (CW - 1);
                int pp = (rn + u) * CW1 + cn + v;
                int ch = kc ^ ((pp >> 1) & 3);
                bfr[nf] = *reinterpret_cast<const bf16x8*>(&XS[pp * 32 + ch * 8]);
            }
            #pragma unroll
            for (int mf = 0; mf < 4; ++mf)
                #pragma unroll
                for (int nf = 0; nf < 2; ++nf)
                    acc[mf][nf] = __builtin_amdgcn_mfma_f32_16x16x32_bf16(
                        af[mf], bfr[nf], acc[mf][nf], 0, 0, 0);
        }
    }

    int kc4 = lane >> 4;
    #pragma unroll
    for (int nf = 0; nf < 2; ++nf) {
        int n = wid * 32 + nf * 16 + l15;
        int rn = n >> cshift, cn = n & (CW - 1);
        int y = 2 * (i0 + rn) + py;
        int xx = 2 * cn + px;
        int pout = y * 2 * Win + xx;
        #pragma unroll
        for (int mf = 0; mf < 4; ++mf) {
            ushort4 hb;
            #pragma unroll
            for (int r = 0; r < 4; ++r) {
                int m = mf * 16 + kc4 * 4 + r;
                int o = o0 + m;
                float s = g[o] * rsqrtf(va[o] + EPSV);
                float v = (acc[mf][nf][r] + bias[o]) * s + (be[o] - mu[o] * s);
                if (res) v += res[((long)(b * Cout) + o) * Pout + pout];
                if (of32) of32[((long)(b * Cout) + o) * Pout + pout] = v;
                ((unsigned short*)&hb)[r] = f2bf(v);
            }
            if (obf)
                *reinterpret_cast<ushort4*>(
                    &obf[(long)(b * Pout + pout) * OCtot + cof + o0 + mf * 16 + kc4 * 4]) = hb;
        }
    }
}

// ---------------- fused lift_net: 512 thr = 64 px x 8 oc-groups, scalar weights ----------------
// grid (R*L/64, nsel, B). blockIdx.y selects input/output set (A or B).
__global__ __launch_bounds__(512) void lift_net_kernel(
    const float* __restrict__ xA, const float* __restrict__ xB,
    const float* __restrict__ oA, const float* __restrict__ oB,
    float* __restrict__ uA, float* __restrict__ uB,
    int x_sB, int x_sC, int x_sR, int x_sA,
    int o_sB, int o_sC, int o_sR, int o_sA,
    int u_sB, int u_sC, int u_sR, int u_sA,
    const float* __restrict__ w1, const float* __restrict__ b1,
    const float* __restrict__ w2, const float* __restrict__ b2,
    int R, int L, int lsh, float sign,
    unsigned short* __restrict__ obf, int Pb, int OCb, int cofA, int cofB)
{
    __shared__ float xsm[4864];   // 64c * rpb * (L+3)
    __shared__ float hsm[8192];   // 128 h x 64 px
    int t = threadIdx.x;
    int g = t & 63, ocg = t >> 6;
    int b = blockIdx.z;
    int sel = blockIdx.y;
    const float* xin = sel ? xB : xA;
    const float* oth = sel ? oB : oA;
    float* outp = sel ? uB : uA;
    int cofb = sel ? cofB : cofA;
    int rpb = 64 >> lsh;
    int row0 = blockIdx.x * rpb;
    int Lp = L + 3;
    int total = 64 * rpb * Lp;
    for (int idx = t; idx < total; idx += 512) {
        int c = idx / (rpb * Lp);
        int rem = idx - c * rpb * Lp;
        int rr_l = rem / Lp;
        int q = rem - rr_l * Lp;
        int s = q - 2;
        s = (s < 0) ? -s : s;
        if (s >= L) s = 2 * L - 2 - s;
        xsm[idx] = xin[b * x_sB + c * x_sC + (row0 + rr_l) * x_sR + s * x_sA];
    }
    __syncthreads();

    int ocgu = __builtin_amdgcn_readfirstlane(ocg);
    int rl = g >> lsh, jl = g & (L - 1);
    const float* w1u = w1 + ocgu * 16 * 256;      // 16 h-channels per group
    float acc1[16] = {};
    for (int c = 0; c < 64; ++c) {
        const float* xr = &xsm[(c * rpb + rl) * Lp + jl];
        float x0 = xr[0], x1 = xr[1], x2 = xr[2], x3 = xr[3];
        const float* wc = w1u + c * 4;
        #pragma unroll
        for (int k = 0; k < 16; ++k) {
            const float* wr = wc + k * 256;
            acc1[k] += wr[0] * x0 + wr[1] * x1 + wr[2] * x2 + wr[3] * x3;
        }
    }
    #pragma unroll
    for (int k = 0; k < 16; ++k) {
        int oc = ocgu * 16 + k;
        hsm[oc * 64 + g] = fmaxf(acc1[k] + b1[oc], 0.f);
    }
    __syncthreads();

    const float* w2u = w2 + ocgu * 8 * 128;       // 8 out-channels per group
    float acc2[8] = {};
    for (int h4 = 0; h4 < 32; ++h4) {
        float hv0 = hsm[(h4 * 4 + 0) * 64 + g];
        float hv1 = hsm[(h4 * 4 + 1) * 64 + g];
        float hv2 = hsm[(h4 * 4 + 2) * 64 + g];
        float hv3 = hsm[(h4 * 4 + 3) * 64 + g];
        #pragma unroll
        for (int kk = 0; kk < 8; ++kk) {
            const float* wr = w2u + kk * 128 + h4 * 4;
            acc2[kk] += wr[0] * hv0 + wr[1] * hv1 + wr[2] * hv2 + wr[3] * hv3;
        }
    }
    int rg = row0 + rl;
    int p = rg * u_sR + jl * u_sA;
    #pragma unroll
    for (int kk = 0; kk < 8; ++kk) {
        int o = ocgu * 8 + kk;
        float v = oth[b * o_sB + o * o_sC + rg * o_sR + jl * o_sA]
                + sign * tanhf(acc2[kk] + b2[o]);
        outp[b * u_sB + o * u_sC + p] = v;
        if (obf) obf[(long)(b * Pb + p) * OCb + cofb + o] = f2bf(v);
    }
}

// ---------------- depthwise 3x3 ----------------
__global__ __launch_bounds__(256) void dw3x3_kernel(
    const float* __restrict__ x, const float* __restrict__ w, const float* __restrict__ bias,
    const float* __restrict__ scale, float* __restrict__ out, int relu_out)
{
    int c = blockIdx.y, b = blockIdx.z;
    int pix = blockIdx.x * 256 + threadIdx.x;
    int y = pix >> 6, xc = pix & 63;
    const float* xp = x + (b * 256 + c) * 4096;
    const float* wc = w + c * 9;
    float acc = bias[c];
    #pragma unroll
    for (int ky = 0; ky < 3; ky++) {
        int yy = y + ky - 1;
        if (yy < 0 || yy > 63) continue;
        #pragma unroll
        for (int kx = 0; kx < 3; kx++) {
            int xx = xc + kx - 1;
            if (xx < 0 || xx > 63) continue;
            acc += wc[ky * 3 + kx] * xp[yy * 64 + xx];
        }
    }
    if (relu_out) acc = fmaxf(acc, 0.f);
    if (scale) acc *= scale[c];
    out[(b * 256 + c) * 4096 + pix] = acc;
}

// ---------------- final gather + residual ----------------
__global__ __launch_bounds__(256) void gather_add_kernel(
    const float* __restrict__ tok, const int* __restrict__ idx,
    const float* __restrict__ t2, float* __restrict__ out)
{
    int i = blockIdx.x * 256 + threadIdx.x;
    int bc = i >> 13;
    out[i] = tok[i] + t2[(bc << 12) + idx[i]];
}

extern "C" void kernel_launch(void* const* d_in, const int* in_sizes, int n_in,
                              void* d_out, int out_size, void* d_ws, size_t ws_size,
                              hipStream_t stream)
{
    const float* tokens = (const float*)d_in[0];
    const float* fm     = (const float*)d_in[1];
    const int*   infl   = (const int*)d_in[2];
    const float* bng = (const float*)d_in[3];
    const float* bnb = (const float*)d_in[4];
    const float* bnm = (const float*)d_in[5];
    const float* bnv = (const float*)d_in[6];
    const float* red_w = (const float*)d_in[7];
    const float* red_b = (const float*)d_in[8];
    const float* lw1 = (const float*)d_in[9];
    const float* lb1 = (const float*)d_in[10];
    const float* lw2 = (const float*)d_in[11];
    const float* lb2 = (const float*)d_in[12];
    const float* f2w1 = (const float*)d_in[13];
    const float* f2b1 = (const float*)d_in[14];
    const float* f2w2 = (const float*)d_in[15];
    const float* f2b2 = (const float*)d_in[16];
    const float* ct2w = (const float*)d_in[17];
    const float* ct2b = (const float*)d_in[18];
    const float* bn2g = (const float*)d_in[19];
    const float* bn2b = (const float*)d_in[20];
    const float* bn2m = (const float*)d_in[21];
    const float* bn2v = (const float*)d_in[22];
    const float* f1w1 = (const float*)d_in[23];
    const float* f1b1 = (const float*)d_in[24];
    const float* f1w2 = (const float*)d_in[25];
    const float* f1b2 = (const float*)d_in[26];
    const float* ct1w = (const float*)d_in[27];
    const float* ct1b = (const float*)d_in[28];
    const float* bn1g = (const float*)d_in[29];
    const float* bn1b = (const float*)d_in[30];
    const float* bn1m = (const float*)d_in[31];
    const float* bn1v = (const float*)d_in[32];
    const float* dw1w = (const float*)d_in[33];
    const float* dw1b = (const float*)d_in[34];
    const float* dw2w = (const float*)d_in[35];
    const float* dw2b = (const float*)d_in[36];
    const float* scw  = (const float*)d_in[37];

    float* ws = (float*)d_ws;
    // layout (float slots), total 11,534,336 = 46.14 MB
    unsigned short* Abf = (unsigned short*)ws;              // [0, 2,097,152) fl
    float* rgrid = ws + 0;                                  // overlaps Abf (dead after flatten)
    float* part  = ws + 2097152;                            // 4 partials x 2,097,152
    unsigned short* rgrid_bf = (unsigned short*)(ws + 10485760); // 1,048,576 fl
    // downstream buffers live inside the dead-partials region after add4_t:
    float* rr    = ws + 2097152;    // 524,288
    float* c1    = ws + 2621440;    // 262,144
    float* d1    = ws + 2883584;    // 262,144
    float* c2    = ws + 3145728;    // 65,536
    float* d2    = ws + 3211264;    // 65,536
    float* x2    = ws + 3276800;    // 131,072
    unsigned short* x2_bf  = (unsigned short*)(ws + 3407872);   // 65,536 fl
    float* x1    = ws + 3473408;    // 786,432
    unsigned short* x1_bf  = (unsigned short*)(ws + 4259840);   // 393,216 fl
    unsigned short* g2_bf  = (unsigned short*)(ws + 4653056);   // 65,536 fl
    unsigned short* y2p_bf = (unsigned short*)(ws + 4718592);   // 65,536 fl
    unsigned short* g1_bf  = (unsigned short*)(ws + 4784128);   // 262,144 fl
    unsigned short* y1p_bf = (unsigned short*)(ws + 5046272);   // 262,144 fl
    unsigned short* wp2    = (unsigned short*)(ws + 5308416);   // 262,144 fl
    unsigned short* wp1    = (unsigned short*)(ws + 5570560);   // 524,288 fl
    float* r2 = ws + 6094848;       // 2,097,152 (ends 8,192,000 < 10,485,760)
    float* t1 = ws + 2097152;       // reuse rr..x1 region (dead at dw1 time)
    float* t2 = rgrid;              // reuse rgrid (dead after convt1 residual)

    // 1. BN -> bf16
    bn_to_bf16_kernel<<<4096, 256, 0, stream>>>((const float4*)tokens, (ushort4*)Abf,
                                                bng, bnb, bnm, bnv);
    // 2. flatten einsum (MFMA, K-split 4) + reduce/transpose
    flatten_gemm_mfma<<<dim3(64, 1, 8), 256, 0, stream>>>(Abf, fm, part);
    add4_t_kernel<<<dim3(64, 4, 2), 256, 0, stream>>>(part, rgrid, rgrid_bf);
    // weight packs (into dead-partials region — must be after add4_t)
    wpack_kernel<<<512, 256, 0, stream>>>(ct1w, wp1, 256, 256);
    wpack_kernel<<<256, 256, 0, stream>>>(ct2w, wp2, 128, 256);
    // 3. reduce 1x1 (256->64), f32 out
    conv1x1_mfma<<<dim3(16, 1, 2), 256, 0, stream>>>(rgrid_bf, red_w, red_b,
                                                     rr, (unsigned short*)nullptr,
                                                     256, 64, 4096, 0);

    auto lift2 = [&](const float* xA, const float* xB, const float* oA, const float* oB,
                     float* uA, float* uB,
                     int xsB, int xsC, int xsR, int xsA,
                     int osB, int osC, int osR, int osA,
                     int usB, int usC, int usR, int usA,
                     int lvl, int sch, int net, int R, int L, float sign,
                     unsigned short* obf, int Pb, int OCb, int cofA, int cofB, int nsel) {
        int widx = (lvl * 2 + sch) * 2 + net;
        int lsh = (L == 32) ? 5 : 4;
        lift_net_kernel<<<dim3(R * L / 64, nsel, 2), 512, 0, stream>>>(
            xA, xB, oA, oB, uA, uB,
            xsB, xsC, xsR, xsA, osB, osC, osR, osA, usB, usC, usR, usA,
            lw1 + widx * 32768, lb1 + widx * 128, lw2 + widx * 8192, lb2 + widx * 64,
            R, L, lsh, sign, obf, Pb, OCb, cofA, cofB);
    };

    // ---- stage 1: L1 horizontal P -> d1 ----
    lift2(rr, rr, rr + 1, rr + 1, d1, d1,
          262144, 4096, 64, 2,  262144, 4096, 64, 2,  131072, 2048, 32, 1,
          0, 0, 0, 64, 32, -1.f, nullptr, 0, 0, 0, 0, 1);
    // ---- stage 2: L1 horizontal U -> c1 ----
    lift2(d1, d1, rr, rr, c1, c1,
          131072, 2048, 32, 1,  262144, 4096, 64, 2,  131072, 2048, 32, 1,
          0, 0, 1, 64, 32, +1.f, nullptr, 0, 0, 0, 0, 1);
    // ---- stage 3: L1 vertical P pair: c1->LH1(ch64), d1->HH1(ch192) ----
    lift2(c1, d1, c1 + 32, d1 + 32, x1 + 65536, x1 + 196608,
          131072, 2048, 1, 64,  131072, 2048, 1, 64,  393216, 1024, 1, 32,
          0, 1, 0, 32, 32, -1.f, x1_bf, 1024, 384, 64, 192, 2);
    // ---- stage 4: L1 vertical U pair: ->LL1(ch0), ->HL1(ch128) ----
    lift2(x1 + 65536, x1 + 196608, c1, d1, x1, x1 + 131072,
          393216, 1024, 1, 32,  131072, 2048, 1, 64,  393216, 1024, 1, 32,
          0, 1, 1, 32, 32, +1.f, x1_bf, 1024, 384, 0, 128, 2);
    // ---- stage 5: L2 horizontal P on LL1 -> d2 ----
    lift2(x1, x1, x1 + 1, x1 + 1, d2, d2,
          393216, 1024, 32, 2,  393216, 1024, 32, 2,  65536, 512, 16, 1,
          1, 0, 0, 32, 16, -1.f, nullptr, 0, 0, 0, 0, 1);
    // ---- stage 6: L2 horizontal U -> c2 ----
    lift2(d2, d2, x1, x1, c2, c2,
          65536, 512, 16, 1,  393216, 1024, 32, 2,  65536, 512, 16, 1,
          1, 0, 1, 32, 16, +1.f, nullptr, 0, 0, 0, 0, 1);
    // ---- stage 7: L2 vertical P pair: c2->LH2(ch64), d2->HH2(ch192) ----
    lift2(c2, d2, c2 + 16, d2 + 16, x2 + 16384, x2 + 49152,
          65536, 512, 1, 32,  65536, 512, 1, 32,  65536, 256, 1, 16,
          1, 1, 0, 16, 16, -1.f, x2_bf, 256, 256, 64, 192, 2);
    // ---- stage 8: L2 vertical U pair: ->LL2(ch0), ->HL2(ch128) ----
    lift2(x2 + 16384, x2 + 49152, c2, d2, x2, x2 + 32768,
          65536, 256, 1, 16,  65536, 512, 1, 32,  65536, 256, 1, 16,
          1, 1, 1, 16, 16, +1.f, x2_bf, 256, 256, 0, 128, 2);

    // ---- ff2 (bf16 chain) + ct2 -> x1_bf ch 256..383 ----
    conv1x1_mfma<<<dim3(1, 4, 2), 256, 0, stream>>>(x2_bf, f2w1, f2b1,
        (float*)nullptr, g2_bf, 256, 256, 256, 2);
    conv1x1_mfma<<<dim3(1, 4, 2), 256, 0, stream>>>(g2_bf, f2w2, f2b2,
        (float*)nullptr, y2p_bf, 256, 256, 256, 0);
    convt_mfma<<<dim3(2, 2, 8), 256, 0, stream>>>(y2p_bf, wp2, ct2b,
        bn2g, bn2b, bn2m, bn2v, (const float*)nullptr,
        (float*)nullptr, x1_bf, 256, 128, 16, 16, 8, 4, 384, 256);

    // ---- ff1 + ct1 (+res rgrid) -> r2 f32 ----
    conv1x1_mfma<<<dim3(4, 4, 2), 256, 0, stream>>>(x1_bf, f1w1, f1b1,
        (float*)nullptr, g1_bf, 384, 256, 1024, 2);
    conv1x1_mfma<<<dim3(4, 4, 2), 256, 0, stream>>>(g1_bf, f1w2, f1b2,
        (float*)nullptr, y1p_bf, 256, 256, 1024, 0);
    convt_mfma<<<dim3(8, 4, 8), 256, 0, stream>>>(y1p_bf, wp1, ct1b,
        bn1g, bn1b, bn1m, bn1v, rgrid,
        r2, (unsigned short*)nullptr, 256, 256, 32, 32, 4, 5, 0, 0);

    // ---- depthwise convs + scale ----
    dw3x3_kernel<<<dim3(16, 256, 2), 256, 0, stream>>>(r2, dw1w, dw1b,
        (const float*)nullptr, t1, 1);
    dw3x3_kernel<<<dim3(16, 256, 2), 256, 0, stream>>>(t1, dw2w, dw2b, scw, t2, 0);

    // ---- inflate gather + residual ----
    gather_add_kernel<<<16384, 256, 0, stream>>>(tokens, infl, t2, (float*)d_out);
}

// Round 5
// 717.671 us; speedup vs baseline: 3.4276x; 1.0494x over previous
//
#include <hip/hip_runtime.h>
#include <math.h>

#define EPSV 1e-5f

typedef __attribute__((ext_vector_type(8))) short bf16x8;
typedef __attribute__((ext_vector_type(4))) float f32x4;
typedef __attribute__((ext_vector_type(8))) unsigned short u16x8;

__device__ inline unsigned short f2bf(float f) {
    unsigned u = __float_as_uint(f);
    unsigned r = (u + 0x7fffu + ((u >> 16) & 1u)) >> 16;
    return (unsigned short)r;
}

__device__ inline void gload_lds16(const void* g, void* l) {
    __builtin_amdgcn_global_load_lds(
        (const __attribute__((address_space(1))) void*)g,
        (__attribute__((address_space(3))) void*)l, 16, 0, 0);
}

// ---------------- BN over tokens (B,C,N) -> bf16 ----------------
__global__ __launch_bounds__(256) void bn_to_bf16_kernel(
    const float4* __restrict__ x, ushort4* __restrict__ y,
    const float* __restrict__ g, const float* __restrict__ be,
    const float* __restrict__ mu, const float* __restrict__ va)
{
    int i = blockIdx.x * 256 + threadIdx.x;
    int c = (i >> 11) & 255;
    float s = g[c] * rsqrtf(va[c] + EPSV);
    float t = be[c] - mu[c] * s;
    float4 v = x[i];
    ushort4 h;
    h.x = f2bf(v.x * s + t); h.y = f2bf(v.y * s + t);
    h.z = f2bf(v.z * s + t); h.w = f2bf(v.w * s + t);
    y[i] = h;
}

// ---------------- MFMA flatten einsum, K-split 8 ----------------
// grid (64, 1, 16): z = b*8 + ks. Each block: BM=256 c, BN=64 m, K-range 1024.
__global__ __launch_bounds__(256) void flatten_gemm_mfma(
    const unsigned short* __restrict__ A, const float* __restrict__ Bm,
    float* __restrict__ Pbase)
{
    __shared__ __align__(16) unsigned short AS[2][256 * 32];
    __shared__ __align__(16) unsigned short BS[2][64 * 32];
    int t = threadIdx.x;
    int wid = t >> 6, lane = t & 63;
    int n0 = blockIdx.x * 64;
    int ks = blockIdx.z & 7, b = blockIdx.z >> 3;
    const unsigned short* Ab = A + b * (256 * 8192);
    const float* Bb = Bm + (long)b * (4096 * 8192) + (long)n0 * 8192;
    int k0 = ks * 1024;
    int brow = t >> 3, bc8 = t & 7;

    f32x4 acc[4][4] = {};

    #pragma unroll
    for (int j = 0; j < 4; ++j) {
        int d16 = (wid * 4 + j) * 64 + lane;
        int row = d16 >> 2;
        int ch = (d16 & 3) ^ ((row >> 1) & 3);
        gload_lds16(Ab + row * 8192 + k0 + ch * 8, &AS[0][(wid * 4 + j) * 512]);
    }
    float4 breg0 = *(const float4*)(Bb + brow * 8192 + k0 + bc8 * 4);
    float4 breg1 = *(const float4*)(Bb + (brow + 32) * 8192 + k0 + bc8 * 4);
    __syncthreads();

    for (int it = 0; it < 32; ++it) {
        int cur = it & 1;
        {
            int ch16 = (bc8 >> 1) ^ ((brow >> 1) & 3);
            ushort4 h;
            h.x = f2bf(breg0.x); h.y = f2bf(breg0.y); h.z = f2bf(breg0.z); h.w = f2bf(breg0.w);
            *reinterpret_cast<ushort4*>(&BS[cur][brow * 32 + ch16 * 8 + (bc8 & 1) * 4]) = h;
            int r2 = brow + 32;
            int ch16b = (bc8 >> 1) ^ ((r2 >> 1) & 3);
            ushort4 h2;
            h2.x = f2bf(breg1.x); h2.y = f2bf(breg1.y); h2.z = f2bf(breg1.z); h2.w = f2bf(breg1.w);
            *reinterpret_cast<ushort4*>(&BS[cur][r2 * 32 + ch16b * 8 + (bc8 & 1) * 4]) = h2;
        }
        __syncthreads();

        if (it < 31) {
            int kn = k0 + (it + 1) * 32;
            #pragma unroll
            for (int j = 0; j < 4; ++j) {
                int d16 = (wid * 4 + j) * 64 + lane;
                int row = d16 >> 2;
                int ch = (d16 & 3) ^ ((row >> 1) & 3);
                gload_lds16(Ab + row * 8192 + kn + ch * 8, &AS[cur ^ 1][(wid * 4 + j) * 512]);
            }
            breg0 = *(const float4*)(Bb + brow * 8192 + kn + bc8 * 4);
            breg1 = *(const float4*)(Bb + (brow + 32) * 8192 + kn + bc8 * 4);
        }

        int l15 = lane & 15, kc = lane >> 4;
        bf16x8 af[4], bfr[4];
        #pragma unroll
        for (int mf = 0; mf < 4; ++mf) {
            int row = wid * 64 + mf * 16 + l15;
            int ch = kc ^ ((row >> 1) & 3);
            af[mf] = *reinterpret_cast<const bf16x8*>(&AS[cur][row * 32 + ch * 8]);
        }
        #pragma unroll
        for (int nf = 0; nf < 4; ++nf) {
            int row = nf * 16 + l15;
            int ch = kc ^ ((row >> 1) & 3);
            bfr[nf] = *reinterpret_cast<const bf16x8*>(&BS[cur][row * 32 + ch * 8]);
        }
        #pragma unroll
        for (int mf = 0; mf < 4; ++mf)
            #pragma unroll
            for (int nf = 0; nf < 4; ++nf)
                acc[mf][nf] = __builtin_amdgcn_mfma_f32_16x16x32_bf16(
                    af[mf], bfr[nf], acc[mf][nf], 0, 0, 0);
        __syncthreads();
    }

    float* P = Pbase + (long)ks * 2097152;
    float* Cb = P + (b * 256) * 4096 + n0;
    #pragma unroll
    for (int mf = 0; mf < 4; ++mf) {
        int rbase = wid * 64 + mf * 16 + (lane >> 4) * 4;
        #pragma unroll
        for (int nf = 0; nf < 4; ++nf) {
            int col = nf * 16 + (lane & 15);
            #pragma unroll
            for (int r = 0; r < 4; ++r)
                Cb[(rbase + r) * 4096 + col] = acc[mf][nf][r];
        }
    }
}

// ---------------- add8 + transpose: rgrid f32 (c,p) and rgrid_bf bf16 (p,c) ----------------
__global__ __launch_bounds__(256) void add8_t_kernel(
    const float* __restrict__ p, float* __restrict__ of32, unsigned short* __restrict__ obf)
{
    __shared__ float tl[64][65];
    int t = threadIdx.x;
    int b = blockIdx.z;
    int c0 = blockIdx.y * 64, p0 = blockIdx.x * 64;
    #pragma unroll
    for (int u = 0; u < 16; ++u) {
        int idx = u * 256 + t;
        int cl = idx >> 6, pl = idx & 63;
        long g = (long)(b * 256 + c0 + cl) * 4096 + p0 + pl;
        float v = 0.f;
        #pragma unroll
        for (int q = 0; q < 8; ++q) v += p[g + (long)q * 2097152];
        tl[cl][pl] = v;
        of32[g] = v;
    }
    __syncthreads();
    #pragma unroll
    for (int u = 0; u < 16; ++u) {
        int idx = u * 256 + t;
        int pl = idx >> 6, cl = idx & 63;
        obf[(long)(b * 4096 + p0 + pl) * 256 + c0 + cl] = f2bf(tl[cl][pl]);
    }
}

// ---------------- weight pack for convT: wp[par][tap][o][c] bf16 ----------------
__global__ __launch_bounds__(256) void wpack_kernel(
    const float* __restrict__ w, unsigned short* __restrict__ wp, int Cout, int Cin)
{
    int id = blockIdx.x * 256 + threadIdx.x;
    int nc8 = Cin >> 3;
    int cch = id % nc8;
    int rest = id / nc8;
    int o = rest % Cout;
    int pt = rest / Cout;
    if (pt >= 16) return;
    int par = pt >> 2, tap = pt & 3;
    int py = par >> 1, px = par & 1, u = tap >> 1, v = tap & 1;
    int tf = (3 - py - 2 * u) * 4 + (3 - px - 2 * v);
    u16x8 h;
    #pragma unroll
    for (int e = 0; e < 8; ++e)
        h[e] = f2bf(w[((cch * 8 + e) * Cout + o) * 16 + tf]);
    *reinterpret_cast<u16x8*>(&wp[((pt * Cout + o) * Cin) + cch * 8]) = h;
}

// ---------------- generic 1x1 conv via MFMA, templated N-tile ----------------
// Block: M=64 couts, N = NF*64 px (4 waves x NF*16). grid (P/(NF*64), Cout/64, B).
template<int NF>
__global__ __launch_bounds__(256) void conv1x1_mfma(
    const unsigned short* __restrict__ xbf, const float* __restrict__ w,
    const float* __restrict__ bias, float* __restrict__ of32,
    unsigned short* __restrict__ obf, int Cin, int Cout, int P, int act)
{
    constexpr int BP = NF * 64;
    __shared__ __align__(16) unsigned short XS[2][BP * 32];
    __shared__ __align__(16) unsigned short WS[2][64 * 32];
    int t = threadIdx.x;
    int wid = t >> 6, lane = t & 63;
    int b = blockIdx.z;
    int p0 = blockIdx.x * BP, o0 = blockIdx.y * 64;
    const unsigned short* xb = xbf + (long)b * P * Cin;
    int wm = t >> 2, wq = t & 3;
    int chunks = Cin >> 5;

    f32x4 acc[4][NF] = {};

    #pragma unroll
    for (int j = 0; j < NF; ++j) {
        int d16 = (wid * NF + j) * 64 + lane;
        int p = d16 >> 2;
        int ch = (d16 & 3) ^ ((p >> 1) & 3);
        gload_lds16(xb + (long)(p0 + p) * Cin + ch * 8, &XS[0][(wid * NF + j) * 512]);
    }
    float4 wr0 = *(const float4*)(w + (o0 + wm) * Cin + wq * 8);
    float4 wr1 = *(const float4*)(w + (o0 + wm) * Cin + wq * 8 + 4);
    __syncthreads();

    for (int cc = 0; cc < chunks; ++cc) {
        int cur = cc & 1;
        {
            int chq = wq ^ ((wm >> 1) & 3);
            u16x8 h;
            h[0] = f2bf(wr0.x); h[1] = f2bf(wr0.y); h[2] = f2bf(wr0.z); h[3] = f2bf(wr0.w);
            h[4] = f2bf(wr1.x); h[5] = f2bf(wr1.y); h[6] = f2bf(wr1.z); h[7] = f2bf(wr1.w);
            *reinterpret_cast<u16x8*>(&WS[cur][wm * 32 + chq * 8]) = h;
        }
        __syncthreads();

        if (cc < chunks - 1) {
            int kn = (cc + 1) * 32;
            #pragma unroll
            for (int j = 0; j < NF; ++j) {
                int d16 = (wid * NF + j) * 64 + lane;
                int p = d16 >> 2;
                int ch = (d16 & 3) ^ ((p >> 1) & 3);
                gload_lds16(xb + (long)(p0 + p) * Cin + kn + ch * 8,
                            &XS[cur ^ 1][(wid * NF + j) * 512]);
            }
            wr0 = *(const float4*)(w + (o0 + wm) * Cin + kn + wq * 8);
            wr1 = *(const float4*)(w + (o0 + wm) * Cin + kn + wq * 8 + 4);
        }

        int l15 = lane & 15, kc = lane >> 4;
        bf16x8 af[4], bfr[NF];
        #pragma unroll
        for (int mf = 0; mf < 4; ++mf) {
            int row = mf * 16 + l15;
            int ch = kc ^ ((row >> 1) & 3);
            af[mf] = *reinterpret_cast<const bf16x8*>(&WS[cur][row * 32 + ch * 8]);
        }
        #pragma unroll
        for (int nf = 0; nf < NF; ++nf) {
            int row = wid * (NF * 16) + nf * 16 + l15;
            int ch = kc ^ ((row >> 1) & 3);
            bfr[nf] = *reinterpret_cast<const bf16x8*>(&XS[cur][row * 32 + ch * 8]);
        }
        #pragma unroll
        for (int mf = 0; mf < 4; ++mf)
            #pragma unroll
            for (int nf = 0; nf < NF; ++nf)
                acc[mf][nf] = __builtin_amdgcn_mfma_f32_16x16x32_bf16(
                    af[mf], bfr[nf], acc[mf][nf], 0, 0, 0);
        __syncthreads();
    }

    int l15 = lane & 15, kc4 = lane >> 4;
    #pragma unroll
    for (int mf = 0; mf < 4; ++mf) {
        #pragma unroll
        for (int nf = 0; nf < NF; ++nf) {
            int p = wid * (NF * 16) + nf * 16 + l15;
            ushort4 hb;
            #pragma unroll
            for (int r = 0; r < 4; ++r) {
                int m = mf * 16 + kc4 * 4 + r;
                float v = acc[mf][nf][r] + bias[o0 + m];
                if (act == 1) v = fmaxf(v, 0.f);
                else if (act == 2) v = 0.5f * v * (1.f + erff(v * 0.70710678118f));
                if (of32) of32[((long)(b * Cout) + o0 + m) * P + p0 + p] = v;
                ((unsigned short*)&hb)[r] = f2bf(v);
            }
            if (obf)
                *reinterpret_cast<ushort4*>(
                    &obf[(long)(b * P + p0 + p) * Cout + o0 + mf * 16 + kc4 * 4]) = hb;
        }
    }
}

// ---------------- ConvTranspose2d(k=4,s=2,p=1) via MFMA parity decomposition ----------------
__global__ __launch_bounds__(256) void convt_mfma(
    const unsigned short* __restrict__ xbf, const unsigned short* __restrict__ wp,
    const float* __restrict__ bias, const float* __restrict__ g,
    const float* __restrict__ be, const float* __restrict__ mu,
    const float* __restrict__ va, const float* __restrict__ res,
    float* __restrict__ of32, unsigned short* __restrict__ obf,
    int Cin, int Cout, int Hin, int Win, int TR, int cshift, int OCtot, int cof)
{
    __shared__ __align__(16) unsigned short XS[165 * 32];
    __shared__ __align__(16) unsigned short WS[4 * 64 * 32];
    int t = threadIdx.x;
    int wid = t >> 6, lane = t & 63;
    int z = blockIdx.z;
    int b = z >> 2, par = z & 3;
    int py = par >> 1, px = par & 1;
    int o0 = blockIdx.y * 64;
    int i0 = blockIdx.x * TR;
    int CW = Win, CW1 = CW + 1;
    int npatch = (TR + 1) * CW1;
    int Pin = Hin * Win, Pout = 4 * Hin * Win;
    const unsigned short* xb = xbf + (long)b * Pin * Cin;
    int chunks = Cin >> 5;
    int l15 = lane & 15, kc = lane >> 4;

    f32x4 acc[4][2] = {};

    for (int cc = 0; cc < chunks; ++cc) {
        __syncthreads();
        for (int idx = t; idx < npatch * 4; idx += 256) {
            int pp = idx >> 2, ql = idx & 3;
            int qs = ql ^ ((pp >> 1) & 3);
            int a = pp / CW1, bcol = pp - a * CW1;
            int iy = i0 - (1 - py) + a;
            int ix = bcol - (1 - px);
            u16x8 v = {};
            if (iy >= 0 && iy < Hin && ix >= 0 && ix < Win)
                v = *reinterpret_cast<const u16x8*>(
                    &xb[(long)(iy * Win + ix) * Cin + cc * 32 + qs * 8]);
            *reinterpret_cast<u16x8*>(&XS[pp * 32 + ql * 8]) = v;
        }
        {
            int m = t >> 2, q = t & 3;
            int chq = q ^ ((m >> 1) & 3);
            #pragma unroll
            for (int tap = 0; tap < 4; ++tap) {
                u16x8 v = *reinterpret_cast<const u16x8*>(
                    &wp[((long)((par * 4 + tap) * Cout + o0 + m)) * Cin + cc * 32 + q * 8]);
                *reinterpret_cast<u16x8*>(&WS[tap * 2048 + m * 32 + chq * 8]) = v;
            }
        }
        __syncthreads();

        #pragma unroll
        for (int tap = 0; tap < 4; ++tap) {
            int u = tap >> 1, v = tap & 1;
            bf16x8 af[4], bfr[2];
            #pragma unroll
            for (int mf = 0; mf < 4; ++mf) {
                int row = mf * 16 + l15;
                int ch = kc ^ ((row >> 1) & 3);
                af[mf] = *reinterpret_cast<const bf16x8*>(&WS[tap * 2048 + row * 32 + ch * 8]);
            }
            #pragma unroll
            for (int nf = 0; nf < 2; ++nf) {
                int n = wid * 32 + nf * 16 + l15;
                int rn = n >> cshift, cn = n & (CW - 1);
                int pp = (rn + u) * CW1 + cn + v;
                int ch = kc ^ ((pp >> 1) & 3);
                bfr[nf] = *reinterpret_cast<const bf16x8*>(&XS[pp * 32 + ch * 8]);
            }
            #pragma unroll
            for (int mf = 0; mf < 4; ++mf)
                #pragma unroll
                for (int nf = 0; nf < 2; ++nf)
                    acc[mf][nf] = __builtin_amdgcn_mfma_f32_16x16x32_bf16(
                        af[mf], bfr[nf], acc[mf][nf], 0, 0, 0);
        }
    }

    int kc4 = lane >> 4;
    #pragma unroll
    for (int nf = 0; nf < 2; ++nf) {
        int n = wid * 32 + nf * 16 + l15;
        int rn = n >> cshift, cn = n & (CW - 1);
        int y = 2 * (i0 + rn) + py;
        int xx = 2 * cn + px;
        int pout = y * 2 * Win + xx;
        #pragma unroll
        for (int mf = 0; mf < 4; ++mf) {
            ushort4 hb;
            #pragma unroll
            for (int r = 0; r < 4; ++r) {
                int m = mf * 16 + kc4 * 4 + r;
                int o = o0 + m;
                float s = g[o] * rsqrtf(va[o] + EPSV);
                float v = (acc[mf][nf][r] + bias[o]) * s + (be[o] - mu[o] * s);
                if (res) v += res[((long)(b * Cout) + o) * Pout + pout];
                if (of32) of32[((long)(b * Cout) + o) * Pout + pout] = v;
                ((unsigned short*)&hb)[r] = f2bf(v);
            }
            if (obf)
                *reinterpret_cast<ushort4*>(
                    &obf[(long)(b * Pout + pout) * OCtot + cof + o0 + mf * 16 + kc4 * 4]) = hb;
        }
    }
}

// ---------------- fused lift_net: 1024 thr = 64 px x 16 oc-groups, scalar weights ----------------
__global__ __launch_bounds__(1024) void lift_net_kernel(
    const float* __restrict__ xA, const float* __restrict__ xB,
    const float* __restrict__ oA, const float* __restrict__ oB,
    float* __restrict__ uA, float* __restrict__ uB,
    int x_sB, int x_sC, int x_sR, int x_sA,
    int o_sB, int o_sC, int o_sR, int o_sA,
    int u_sB, int u_sC, int u_sR, int u_sA,
    const float* __restrict__ w1, const float* __restrict__ b1,
    const float* __restrict__ w2, const float* __restrict__ b2,
    int R, int L, int lsh, float sign,
    unsigned short* __restrict__ obf, int Pb, int OCb, int cofA, int cofB)
{
    __shared__ float xsm[4864];   // 64c * rpb * (L+3)
    __shared__ float hsm[8192];   // 128 h x 64 px
    int t = threadIdx.x;
    int g = t & 63, ocg = t >> 6;           // 16 groups
    int b = blockIdx.z;
    int sel = blockIdx.y;
    const float* xin = sel ? xB : xA;
    const float* oth = sel ? oB : oA;
    float* outp = sel ? uB : uA;
    int cofb = sel ? cofB : cofA;
    int rpb = 64 >> lsh;
    int row0 = blockIdx.x * rpb;
    int Lp = L + 3;
    int total = 64 * rpb * Lp;
    for (int idx = t; idx < total; idx += 1024) {
        int c = idx / (rpb * Lp);
        int rem = idx - c * rpb * Lp;
        int rr_l = rem / Lp;
        int q = rem - rr_l * Lp;
        int s = q - 2;
        s = (s < 0) ? -s : s;
        if (s >= L) s = 2 * L - 2 - s;
        xsm[idx] = xin[b * x_sB + c * x_sC + (row0 + rr_l) * x_sR + s * x_sA];
    }
    __syncthreads();

    int ocgu = __builtin_amdgcn_readfirstlane(ocg);
    int rl = g >> lsh, jl = g & (L - 1);
    const float* w1u = w1 + ocgu * 8 * 256;       // 8 h-channels per group
    float acc1[8] = {};
    for (int c = 0; c < 64; ++c) {
        const float* xr = &xsm[(c * rpb + rl) * Lp + jl];
        float x0 = xr[0], x1 = xr[1], x2 = xr[2], x3 = xr[3];
        const float* wc = w1u + c * 4;
        #pragma unroll
        for (int k = 0; k < 8; ++k) {
            const float* wr = wc + k * 256;
            acc1[k] += wr[0] * x0 + wr[1] * x1 + wr[2] * x2 + wr[3] * x3;
        }
    }
    #pragma unroll
    for (int k = 0; k < 8; ++k) {
        int oc = ocgu * 8 + k;
        hsm[oc * 64 + g] = fmaxf(acc1[k] + b1[oc], 0.f);
    }
    __syncthreads();

    const float* w2u = w2 + ocgu * 4 * 128;       // 4 out-channels per group
    float acc2[4] = {};
    for (int h4 = 0; h4 < 32; ++h4) {
        float hv0 = hsm[(h4 * 4 + 0) * 64 + g];
        float hv1 = hsm[(h4 * 4 + 1) * 64 + g];
        float hv2 = hsm[(h4 * 4 + 2) * 64 + g];
        float hv3 = hsm[(h4 * 4 + 3) * 64 + g];
        #pragma unroll
        for (int kk = 0; kk < 4; ++kk) {
            const float* wr = w2u + kk * 128 + h4 * 4;
            acc2[kk] += wr[0] * hv0 + wr[1] * hv1 + wr[2] * hv2 + wr[3] * hv3;
        }
    }
    int rg = row0 + rl;
    int p = rg * u_sR + jl * u_sA;
    #pragma unroll
    for (int kk = 0; kk < 4; ++kk) {
        int o = ocgu * 4 + kk;
        float v = oth[b * o_sB + o * o_sC + rg * o_sR + jl * o_sA]
                + sign * tanhf(acc2[kk] + b2[o]);
        outp[b * u_sB + o * u_sC + p] = v;
        if (obf) obf[(long)(b * Pb + p) * OCb + cofb + o] = f2bf(v);
    }
}

// ---------------- depthwise 3x3 ----------------
__global__ __launch_bounds__(256) void dw3x3_kernel(
    const float* __restrict__ x, const float* __restrict__ w, const float* __restrict__ bias,
    const float* __restrict__ scale, float* __restrict__ out, int relu_out)
{
    int c = blockIdx.y, b = blockIdx.z;
    int pix = blockIdx.x * 256 + threadIdx.x;
    int y = pix >> 6, xc = pix & 63;
    const float* xp = x + (b * 256 + c) * 4096;
    const float* wc = w + c * 9;
    float acc = bias[c];
    #pragma unroll
    for (int ky = 0; ky < 3; ky++) {
        int yy = y + ky - 1;
        if (yy < 0 || yy > 63) continue;
        #pragma unroll
        for (int kx = 0; kx < 3; kx++) {
            int xx = xc + kx - 1;
            if (xx < 0 || xx > 63) continue;
            acc += wc[ky * 3 + kx] * xp[yy * 64 + xx];
        }
    }
    if (relu_out) acc = fmaxf(acc, 0.f);
    if (scale) acc *= scale[c];
    out[(b * 256 + c) * 4096 + pix] = acc;
}

// ---------------- final gather + residual ----------------
__global__ __launch_bounds__(256) void gather_add_kernel(
    const float* __restrict__ tok, const int* __restrict__ idx,
    const float* __restrict__ t2, float* __restrict__ out)
{
    int i = blockIdx.x * 256 + threadIdx.x;
    int bc = i >> 13;
    out[i] = tok[i] + t2[(bc << 12) + idx[i]];
}

extern "C" void kernel_launch(void* const* d_in, const int* in_sizes, int n_in,
                              void* d_out, int out_size, void* d_ws, size_t ws_size,
                              hipStream_t stream)
{
    const float* tokens = (const float*)d_in[0];
    const float* fm     = (const float*)d_in[1];
    const int*   infl   = (const int*)d_in[2];
    const float* bng = (const float*)d_in[3];
    const float* bnb = (const float*)d_in[4];
    const float* bnm = (const float*)d_in[5];
    const float* bnv = (const float*)d_in[6];
    const float* red_w = (const float*)d_in[7];
    const float* red_b = (const float*)d_in[8];
    const float* lw1 = (const float*)d_in[9];
    const float* lb1 = (const float*)d_in[10];
    const float* lw2 = (const float*)d_in[11];
    const float* lb2 = (const float*)d_in[12];
    const float* f2w1 = (const float*)d_in[13];
    const float* f2b1 = (const float*)d_in[14];
    const float* f2w2 = (const float*)d_in[15];
    const float* f2b2 = (const float*)d_in[16];
    const float* ct2w = (const float*)d_in[17];
    const float* ct2b = (const float*)d_in[18];
    const float* bn2g = (const float*)d_in[19];
    const float* bn2b = (const float*)d_in[20];
    const float* bn2m = (const float*)d_in[21];
    const float* bn2v = (const float*)d_in[22];
    const float* f1w1 = (const float*)d_in[23];
    const float* f1b1 = (const float*)d_in[24];
    const float* f1w2 = (const float*)d_in[25];
    const float* f1b2 = (const float*)d_in[26];
    const float* ct1w = (const float*)d_in[27];
    const float* ct1b = (const float*)d_in[28];
    const float* bn1g = (const float*)d_in[29];
    const float* bn1b = (const float*)d_in[30];
    const float* bn1m = (const float*)d_in[31];
    const float* bn1v = (const float*)d_in[32];
    const float* dw1w = (const float*)d_in[33];
    const float* dw1b = (const float*)d_in[34];
    const float* dw2w = (const float*)d_in[35];
    const float* dw2b = (const float*)d_in[36];
    const float* scw  = (const float*)d_in[37];

    float* ws = (float*)d_ws;
    // spacious layout (ws is 1 GiB): ~129 MB used, no overlaps
    unsigned short* Abf = (unsigned short*)ws;                    // 2,097,152 fl
    float* part  = ws + 2097152;                                  // 8 x 2,097,152 fl
    float* rgrid = ws + 18874368;                                 // 2,097,152
    unsigned short* rgrid_bf = (unsigned short*)(ws + 20971520);  // 1,048,576 fl
    float* rr    = ws + 22020096;   // 524,288
    float* c1    = ws + 22544384;   // 262,144
    float* d1    = ws + 22806528;   // 262,144
    float* c2    = ws + 23068672;   // 65,536
    float* d2    = ws + 23134208;   // 65,536
    float* x2    = ws + 23199744;   // 131,072
    unsigned short* x2_bf  = (unsigned short*)(ws + 23330816);    // 65,536 fl
    float* x1    = ws + 23396352;   // 786,432
    unsigned short* x1_bf  = (unsigned short*)(ws + 24182784);    // 393,216 fl
    unsigned short* g2_bf  = (unsigned short*)(ws + 24576000);    // 65,536 fl
    unsigned short* y2p_bf = (unsigned short*)(ws + 24641536);    // 65,536 fl
    unsigned short* g1_bf  = (unsigned short*)(ws + 24707072);    // 262,144 fl
    unsigned short* y1p_bf = (unsigned short*)(ws + 24969216);    // 262,144 fl
    unsigned short* wp2    = (unsigned short*)(ws + 25231360);    // 262,144 fl
    unsigned short* wp1    = (unsigned short*)(ws + 25493504);    // 524,288 fl
    float* r2 = ws + 26017792;      // 2,097,152
    float* t1 = ws + 28114944;      // 2,097,152
    float* t2 = ws + 30212096;      // 2,097,152

    // weight packs (independent)
    wpack_kernel<<<512, 256, 0, stream>>>(ct1w, wp1, 256, 256);
    wpack_kernel<<<256, 256, 0, stream>>>(ct2w, wp2, 128, 256);

    // 1. BN -> bf16
    bn_to_bf16_kernel<<<4096, 256, 0, stream>>>((const float4*)tokens, (ushort4*)Abf,
                                                bng, bnb, bnm, bnv);
    // 2. flatten einsum (MFMA, K-split 8) + reduce/transpose
    flatten_gemm_mfma<<<dim3(64, 1, 16), 256, 0, stream>>>(Abf, fm, part);
    add8_t_kernel<<<dim3(64, 4, 2), 256, 0, stream>>>(part, rgrid, rgrid_bf);
    // 3. reduce 1x1 (256->64), f32 out
    conv1x1_mfma<2><<<dim3(32, 1, 2), 256, 0, stream>>>(rgrid_bf, red_w, red_b,
                                                        rr, (unsigned short*)nullptr,
                                                        256, 64, 4096, 0);

    auto lift2 = [&](const float* xA, const float* xB, const float* oA, const float* oB,
                     float* uA, float* uB,
                     int xsB, int xsC, int xsR, int xsA,
                     int osB, int osC, int osR, int osA,
                     int usB, int usC, int usR, int usA,
                     int lvl, int sch, int net, int R, int L, float sign,
                     unsigned short* obf, int Pb, int OCb, int cofA, int cofB, int nsel) {
        int widx = (lvl * 2 + sch) * 2 + net;
        int lsh = (L == 32) ? 5 : 4;
        lift_net_kernel<<<dim3(R * L / 64, nsel, 2), 1024, 0, stream>>>(
            xA, xB, oA, oB, uA, uB,
            xsB, xsC, xsR, xsA, osB, osC, osR, osA, usB, usC, usR, usA,
            lw1 + widx * 32768, lb1 + widx * 128, lw2 + widx * 8192, lb2 + widx * 64,
            R, L, lsh, sign, obf, Pb, OCb, cofA, cofB);
    };

    // ---- stage 1: L1 horizontal P -> d1 ----
    lift2(rr, rr, rr + 1, rr + 1, d1, d1,
          262144, 4096, 64, 2,  262144, 4096, 64, 2,  131072, 2048, 32, 1,
          0, 0, 0, 64, 32, -1.f, nullptr, 0, 0, 0, 0, 1);
    // ---- stage 2: L1 horizontal U -> c1 ----
    lift2(d1, d1, rr, rr, c1, c1,
          131072, 2048, 32, 1,  262144, 4096, 64, 2,  131072, 2048, 32, 1,
          0, 0, 1, 64, 32, +1.f, nullptr, 0, 0, 0, 0, 1);
    // ---- stage 3: L1 vertical P pair: c1->LH1(ch64), d1->HH1(ch192) ----
    lift2(c1, d1, c1 + 32, d1 + 32, x1 + 65536, x1 + 196608,
          131072, 2048, 1, 64,  131072, 2048, 1, 64,  393216, 1024, 1, 32,
          0, 1, 0, 32, 32, -1.f, x1_bf, 1024, 384, 64, 192, 2);
    // ---- stage 4: L1 vertical U pair: ->LL1(ch0), ->HL1(ch128) ----
    lift2(x1 + 65536, x1 + 196608, c1, d1, x1, x1 + 131072,
          393216, 1024, 1, 32,  131072, 2048, 1, 64,  393216, 1024, 1, 32,
          0, 1, 1, 32, 32, +1.f, x1_bf, 1024, 384, 0, 128, 2);
    // ---- stage 5: L2 horizontal P on LL1 -> d2 ----
    lift2(x1, x1, x1 + 1, x1 + 1, d2, d2,
          393216, 1024, 32, 2,  393216, 1024, 32, 2,  65536, 512, 16, 1,
          1, 0, 0, 32, 16, -1.f, nullptr, 0, 0, 0, 0, 1);
    // ---- stage 6: L2 horizontal U -> c2 ----
    lift2(d2, d2, x1, x1, c2, c2,
          65536, 512, 16, 1,  393216, 1024, 32, 2,  65536, 512, 16, 1,
          1, 0, 1, 32, 16, +1.f, nullptr, 0, 0, 0, 0, 1);
    // ---- stage 7: L2 vertical P pair: c2->LH2(ch64), d2->HH2(ch192) ----
    lift2(c2, d2, c2 + 16, d2 + 16, x2 + 16384, x2 + 49152,
          65536, 512, 1, 32,  65536, 512, 1, 32,  65536, 256, 1, 16,
          1, 1, 0, 16, 16, -1.f, x2_bf, 256, 256, 64, 192, 2);
    // ---- stage 8: L2 vertical U pair: ->LL2(ch0), ->HL2(ch128) ----
    lift2(x2 + 16384, x2 + 49152, c2, d2, x2, x2 + 32768,
          65536, 256, 1, 16,  65536, 512, 1, 32,  65536, 256, 1, 16,
          1, 1, 1, 16, 16, +1.f, x2_bf, 256, 256, 0, 128, 2);

    // ---- ff2 (bf16 chain) + ct2 -> x1_bf ch 256..383 ----
    conv1x1_mfma<1><<<dim3(4, 4, 2), 256, 0, stream>>>(x2_bf, f2w1, f2b1,
        (float*)nullptr, g2_bf, 256, 256, 256, 2);
    conv1x1_mfma<1><<<dim3(4, 4, 2), 256, 0, stream>>>(g2_bf, f2w2, f2b2,
        (float*)nullptr, y2p_bf, 256, 256, 256, 0);
    convt_mfma<<<dim3(2, 2, 8), 256, 0, stream>>>(y2p_bf, wp2, ct2b,
        bn2g, bn2b, bn2m, bn2v, (const float*)nullptr,
        (float*)nullptr, x1_bf, 256, 128, 16, 16, 8, 4, 384, 256);

    // ---- ff1 + ct1 (+res rgrid) -> r2 f32 ----
    conv1x1_mfma<2><<<dim3(8, 4, 2), 256, 0, stream>>>(x1_bf, f1w1, f1b1,
        (float*)nullptr, g1_bf, 384, 256, 1024, 2);
    conv1x1_mfma<2><<<dim3(8, 4, 2), 256, 0, stream>>>(g1_bf, f1w2, f1b2,
        (float*)nullptr, y1p_bf, 256, 256, 1024, 0);
    convt_mfma<<<dim3(8, 4, 8), 256, 0, stream>>>(y1p_bf, wp1, ct1b,
        bn1g, bn1b, bn1m, bn1v, rgrid,
        r2, (unsigned short*)nullptr, 256, 256, 32, 32, 4, 5, 0, 0);

    // ---- depthwise convs + scale ----
    dw3x3_kernel<<<dim3(16, 256, 2), 256, 0, stream>>>(r2, dw1w, dw1b,
        (const float*)nullptr, t1, 1);
    dw3x3_kernel<<<dim3(16, 256, 2), 256, 0, stream>>>(t1, dw2w, dw2b, scw, t2, 0);

    // ---- inflate gather + residual ----
    gather_add_kernel<<<16384, 256, 0, stream>>>(tokens, infl, t2, (float*)d_out);
}

// Round 6
// 671.409 us; speedup vs baseline: 3.6638x; 1.0689x over previous
//
#include <hip/hip_runtime.h>
#include <math.h>

#define EPSV 1e-5f

typedef __attribute__((ext_vector_type(8))) short bf16x8;
typedef __attribute__((ext_vector_type(4))) float f32x4;
typedef __attribute__((ext_vector_type(8))) unsigned short u16x8;

__device__ inline unsigned short f2bf(float f) {
    unsigned u = __float_as_uint(f);
    unsigned r = (u + 0x7fffu + ((u >> 16) & 1u)) >> 16;
    return (unsigned short)r;
}

__device__ inline void gload_lds16(const void* g, void* l) {
    __builtin_amdgcn_global_load_lds(
        (const __attribute__((address_space(1))) void*)g,
        (__attribute__((address_space(3))) void*)l, 16, 0, 0);
}

// ---------------- BN over tokens (B,C,N) -> bf16 ----------------
__global__ __launch_bounds__(256) void bn_to_bf16_kernel(
    const float4* __restrict__ x, ushort4* __restrict__ y,
    const float* __restrict__ g, const float* __restrict__ be,
    const float* __restrict__ mu, const float* __restrict__ va)
{
    int i = blockIdx.x * 256 + threadIdx.x;
    int c = (i >> 11) & 255;
    float s = g[c] * rsqrtf(va[c] + EPSV);
    float t = be[c] - mu[c] * s;
    float4 v = x[i];
    ushort4 h;
    h.x = f2bf(v.x * s + t); h.y = f2bf(v.y * s + t);
    h.z = f2bf(v.z * s + t); h.w = f2bf(v.w * s + t);
    y[i] = h;
}

// ---------------- MFMA flatten einsum: counted-vmcnt pipeline, K-split 4 ----------------
// grid (64, 1, 8): z = b*4 + ks. BM=256 c, BN=64 m, BK=32, 64 K-tiles per block.
// 4 LDS buffers, 3-deep prefetch, ONE raw barrier per tile with vmcnt(8) (never 0).
__global__ __launch_bounds__(256) void flatten_gemm_mfma(
    const unsigned short* __restrict__ A, const float* __restrict__ Bm,
    float* __restrict__ Pbase)
{
    __shared__ __align__(16) unsigned short AS[4][256 * 32];   // 4 x 16 KB
    __shared__ __align__(16) unsigned short BS[4][64 * 32];    // 4 x 4 KB
    const int NTT = 64;
    int t = threadIdx.x;
    int wid = t >> 6, lane = t & 63;
    int n0 = blockIdx.x * 64;
    int ks = blockIdx.z & 3, b = blockIdx.z >> 2;
    const unsigned short* Ab = A + b * (256 * 8192);
    const float* Bb = Bm + (long)b * (4096 * 8192) + (long)n0 * 8192;
    int k0 = ks * 2048;
    int brow = t >> 3, bc8 = t & 7;
    int l15 = lane & 15, kc = lane >> 4;

    f32x4 acc[4][4] = {};

    auto issueA = [&](int tile, int buf) {
        int kb = k0 + tile * 32;
        #pragma unroll
        for (int j = 0; j < 4; ++j) {
            int d16 = (wid * 4 + j) * 64 + lane;
            int row = d16 >> 2;
            int ch = (d16 & 3) ^ ((row >> 1) & 3);
            gload_lds16(Ab + row * 8192 + kb + ch * 8, &AS[buf][(wid * 4 + j) * 512]);
        }
    };
    auto loadB = [&](int tile, float4& f0, float4& f1) {
        int kb = k0 + tile * 32;
        f0 = *(const float4*)(Bb + brow * 8192 + kb + bc8 * 4);
        f1 = *(const float4*)(Bb + (brow + 32) * 8192 + kb + bc8 * 4);
    };
    auto writeB = [&](int buf, const float4& f0, const float4& f1) {
        int ch16 = (bc8 >> 1) ^ ((brow >> 1) & 3);
        ushort4 h;
        h.x = f2bf(f0.x); h.y = f2bf(f0.y); h.z = f2bf(f0.z); h.w = f2bf(f0.w);
        *reinterpret_cast<ushort4*>(&BS[buf][brow * 32 + ch16 * 8 + (bc8 & 1) * 4]) = h;
        int rr2 = brow + 32;
        int ch16b = (bc8 >> 1) ^ ((rr2 >> 1) & 3);
        ushort4 h2;
        h2.x = f2bf(f1.x); h2.y = f2bf(f1.y); h2.z = f2bf(f1.z); h2.w = f2bf(f1.w);
        *reinterpret_cast<ushort4*>(&BS[buf][rr2 * 32 + ch16b * 8 + (bc8 & 1) * 4]) = h2;
    };
    auto mmac = [&](int buf) {
        bf16x8 af[4], bfr[4];
        #pragma unroll
        for (int mf = 0; mf < 4; ++mf) {
            int row = wid * 64 + mf * 16 + l15;
            int ch = kc ^ ((row >> 1) & 3);
            af[mf] = *reinterpret_cast<const bf16x8*>(&AS[buf][row * 32 + ch * 8]);
        }
        #pragma unroll
        for (int nf = 0; nf < 4; ++nf) {
            int row = nf * 16 + l15;
            int ch = kc ^ ((row >> 1) & 3);
            bfr[nf] = *reinterpret_cast<const bf16x8*>(&BS[buf][row * 32 + ch * 8]);
        }
        #pragma unroll
        for (int mf = 0; mf < 4; ++mf)
            #pragma unroll
            for (int nf = 0; nf < 4; ++nf)
                acc[mf][nf] = __builtin_amdgcn_mfma_f32_16x16x32_bf16(
                    af[mf], bfr[nf], acc[mf][nf], 0, 0, 0);
    };

    // ---- prologue: tiles 0,1,2 staged; BS[0],BS[1] written; bregs(2) kept in q ----
    float4 p0, p1, e0, e1, q0, q1, r0, r1;
    loadB(0, p0, p1);
    loadB(1, e0, e1);
    loadB(2, q0, q1);
    issueA(0, 0); issueA(1, 1); issueA(2, 2);
    writeB(0, p0, p1);
    writeB(1, e0, e1);
    // A0 must be complete; A1(4)+A2(4) guaranteed newer -> vmcnt(8)
    asm volatile("s_waitcnt vmcnt(8) lgkmcnt(0)" ::: "memory");
    __builtin_amdgcn_s_barrier();
    __builtin_amdgcn_sched_barrier(0);

    for (int tau = 0; tau < NTT; ++tau) {
        int cur = tau & 3;
        if (tau + 3 < NTT) {           // prefetch tile tau+3
            loadB(tau + 3, r0, r1);
            issueA(tau + 3, (tau + 3) & 3);
        }
        if (tau + 2 < NTT)             // publish B for tile tau+2 (q loaded last iter)
            writeB((tau + 2) & 3, q0, q1);
        mmac(cur);
        // A(tau+1) must complete before next tile's reads.
        // Guaranteed-newer glds: A(tau+2)+A(tau+3) = 8 while both exist.
        if (tau < NTT - 3)
            asm volatile("s_waitcnt vmcnt(8) lgkmcnt(0)" ::: "memory");
        else if (tau == NTT - 3)
            asm volatile("s_waitcnt vmcnt(4) lgkmcnt(0)" ::: "memory");
        else
            asm volatile("s_waitcnt vmcnt(0) lgkmcnt(0)" ::: "memory");
        __builtin_amdgcn_s_barrier();
        __builtin_amdgcn_sched_barrier(0);
        q0 = r0; q1 = r1;
    }

    float* P = Pbase + (long)ks * 2097152;
    float* Cb = P + (b * 256) * 4096 + n0;
    #pragma unroll
    for (int mf = 0; mf < 4; ++mf) {
        int rbase = wid * 64 + mf * 16 + (lane >> 4) * 4;
        #pragma unroll
        for (int nf = 0; nf < 4; ++nf) {
            int col = nf * 16 + (lane & 15);
            #pragma unroll
            for (int r = 0; r < 4; ++r)
                Cb[(rbase + r) * 4096 + col] = acc[mf][nf][r];
        }
    }
}

// ---------------- add4 + transpose: rgrid f32 (c,p) and rgrid_bf bf16 (p,c) ----------------
__global__ __launch_bounds__(256) void add4_t_kernel(
    const float* __restrict__ p, float* __restrict__ of32, unsigned short* __restrict__ obf)
{
    __shared__ float tl[64][65];
    int t = threadIdx.x;
    int b = blockIdx.z;
    int c0 = blockIdx.y * 64, p0 = blockIdx.x * 64;
    #pragma unroll
    for (int u = 0; u < 16; ++u) {
        int idx = u * 256 + t;
        int cl = idx >> 6, pl = idx & 63;
        long g = (long)(b * 256 + c0 + cl) * 4096 + p0 + pl;
        float v = p[g] + p[g + 2097152] + p[g + 2 * 2097152] + p[g + 3 * 2097152];
        tl[cl][pl] = v;
        of32[g] = v;
    }
    __syncthreads();
    #pragma unroll
    for (int u = 0; u < 16; ++u) {
        int idx = u * 256 + t;
        int pl = idx >> 6, cl = idx & 63;
        obf[(long)(b * 4096 + p0 + pl) * 256 + c0 + cl] = f2bf(tl[cl][pl]);
    }
}

// ---------------- weight pack for convT: wp[par][tap][o][c] bf16 ----------------
__global__ __launch_bounds__(256) void wpack_kernel(
    const float* __restrict__ w, unsigned short* __restrict__ wp, int Cout, int Cin)
{
    int id = blockIdx.x * 256 + threadIdx.x;
    int nc8 = Cin >> 3;
    int cch = id % nc8;
    int rest = id / nc8;
    int o = rest % Cout;
    int pt = rest / Cout;
    if (pt >= 16) return;
    int par = pt >> 2, tap = pt & 3;
    int py = par >> 1, px = par & 1, u = tap >> 1, v = tap & 1;
    int tf = (3 - py - 2 * u) * 4 + (3 - px - 2 * v);
    u16x8 h;
    #pragma unroll
    for (int e = 0; e < 8; ++e)
        h[e] = f2bf(w[((cch * 8 + e) * Cout + o) * 16 + tf]);
    *reinterpret_cast<u16x8*>(&wp[((pt * Cout + o) * Cin) + cch * 8]) = h;
}

// ---------------- generic 1x1 conv via MFMA, templated N-tile ----------------
template<int NF>
__global__ __launch_bounds__(256) void conv1x1_mfma(
    const unsigned short* __restrict__ xbf, const float* __restrict__ w,
    const float* __restrict__ bias, float* __restrict__ of32,
    unsigned short* __restrict__ obf, int Cin, int Cout, int P, int act)
{
    constexpr int BP = NF * 64;
    __shared__ __align__(16) unsigned short XS[2][BP * 32];
    __shared__ __align__(16) unsigned short WS[2][64 * 32];
    int t = threadIdx.x;
    int wid = t >> 6, lane = t & 63;
    int b = blockIdx.z;
    int p0 = blockIdx.x * BP, o0 = blockIdx.y * 64;
    const unsigned short* xb = xbf + (long)b * P * Cin;
    int wm = t >> 2, wq = t & 3;
    int chunks = Cin >> 5;

    f32x4 acc[4][NF] = {};

    #pragma unroll
    for (int j = 0; j < NF; ++j) {
        int d16 = (wid * NF + j) * 64 + lane;
        int p = d16 >> 2;
        int ch = (d16 & 3) ^ ((p >> 1) & 3);
        gload_lds16(xb + (long)(p0 + p) * Cin + ch * 8, &XS[0][(wid * NF + j) * 512]);
    }
    float4 wr0 = *(const float4*)(w + (o0 + wm) * Cin + wq * 8);
    float4 wr1 = *(const float4*)(w + (o0 + wm) * Cin + wq * 8 + 4);
    __syncthreads();

    for (int cc = 0; cc < chunks; ++cc) {
        int cur = cc & 1;
        {
            int chq = wq ^ ((wm >> 1) & 3);
            u16x8 h;
            h[0] = f2bf(wr0.x); h[1] = f2bf(wr0.y); h[2] = f2bf(wr0.z); h[3] = f2bf(wr0.w);
            h[4] = f2bf(wr1.x); h[5] = f2bf(wr1.y); h[6] = f2bf(wr1.z); h[7] = f2bf(wr1.w);
            *reinterpret_cast<u16x8*>(&WS[cur][wm * 32 + chq * 8]) = h;
        }
        __syncthreads();

        if (cc < chunks - 1) {
            int kn = (cc + 1) * 32;
            #pragma unroll
            for (int j = 0; j < NF; ++j) {
                int d16 = (wid * NF + j) * 64 + lane;
                int p = d16 >> 2;
                int ch = (d16 & 3) ^ ((p >> 1) & 3);
                gload_lds16(xb + (long)(p0 + p) * Cin + kn + ch * 8,
                            &XS[cur ^ 1][(wid * NF + j) * 512]);
            }
            wr0 = *(const float4*)(w + (o0 + wm) * Cin + kn + wq * 8);
            wr1 = *(const float4*)(w + (o0 + wm) * Cin + kn + wq * 8 + 4);
        }

        int l15 = lane & 15, kc = lane >> 4;
        bf16x8 af[4], bfr[NF];
        #pragma unroll
        for (int mf = 0; mf < 4; ++mf) {
            int row = mf * 16 + l15;
            int ch = kc ^ ((row >> 1) & 3);
            af[mf] = *reinterpret_cast<const bf16x8*>(&WS[cur][row * 32 + ch * 8]);
        }
        #pragma unroll
        for (int nf = 0; nf < NF; ++nf) {
            int row = wid * (NF * 16) + nf * 16 + l15;
            int ch = kc ^ ((row >> 1) & 3);
            bfr[nf] = *reinterpret_cast<const bf16x8*>(&XS[cur][row * 32 + ch * 8]);
        }
        #pragma unroll
        for (int mf = 0; mf < 4; ++mf)
            #pragma unroll
            for (int nf = 0; nf < NF; ++nf)
                acc[mf][nf] = __builtin_amdgcn_mfma_f32_16x16x32_bf16(
                    af[mf], bfr[nf], acc[mf][nf], 0, 0, 0);
        __syncthreads();
    }

    int l15 = lane & 15, kc4 = lane >> 4;
    #pragma unroll
    for (int mf = 0; mf < 4; ++mf) {
        #pragma unroll
        for (int nf = 0; nf < NF; ++nf) {
            int p = wid * (NF * 16) + nf * 16 + l15;
            ushort4 hb;
            #pragma unroll
            for (int r = 0; r < 4; ++r) {
                int m = mf * 16 + kc4 * 4 + r;
                float v = acc[mf][nf][r] + bias[o0 + m];
                if (act == 1) v = fmaxf(v, 0.f);
                else if (act == 2) v = 0.5f * v * (1.f + erff(v * 0.70710678118f));
                if (of32) of32[((long)(b * Cout) + o0 + m) * P + p0 + p] = v;
                ((unsigned short*)&hb)[r] = f2bf(v);
            }
            if (obf)
                *reinterpret_cast<ushort4*>(
                    &obf[(long)(b * P + p0 + p) * Cout + o0 + mf * 16 + kc4 * 4]) = hb;
        }
    }
}

// ---------------- ConvTranspose2d(k=4,s=2,p=1) via MFMA parity decomposition ----------------
__global__ __launch_bounds__(256) void convt_mfma(
    const unsigned short* __restrict__ xbf, const unsigned short* __restrict__ wp,
    const float* __restrict__ bias, const float* __restrict__ g,
    const float* __restrict__ be, const float* __restrict__ mu,
    const float* __restrict__ va, const float* __restrict__ res,
    float* __restrict__ of32, unsigned short* __restrict__ obf,
    int Cin, int Cout, int Hin, int Win, int TR, int cshift, int OCtot, int cof)
{
    __shared__ __align__(16) unsigned short XS[165 * 32];
    __shared__ __align__(16) unsigned short WS[4 * 64 * 32];
    int t = threadIdx.x;
    int wid = t >> 6, lane = t & 63;
    int z = blockIdx.z;
    int b = z >> 2, par = z & 3;
    int py = par >> 1, px = par & 1;
    int o0 = blockIdx.y * 64;
    int i0 = blockIdx.x * TR;
    int CW = Win, CW1 = CW + 1;
    int npatch = (TR + 1) * CW1;
    int Pin = Hin * Win, Pout = 4 * Hin * Win;
    const unsigned short* xb = xbf + (long)b * Pin * Cin;
    int chunks = Cin >> 5;
    int l15 = lane & 15, kc = lane >> 4;

    f32x4 acc[4][2] = {};

    for (int cc = 0; cc < chunks; ++cc) {
        __syncthreads();
        for (int idx = t; idx < npatch * 4; idx += 256) {
            int pp = idx >> 2, ql = idx & 3;
            int qs = ql ^ ((pp >> 1) & 3);
            int a = pp / CW1, bcol = pp - a * CW1;
            int iy = i0 - (1 - py) + a;
            int ix = bcol - (1 - px);
            u16x8 v = {};
            if (iy >= 0 && iy < Hin && ix >= 0 && ix < Win)
                v = *reinterpret_cast<const u16x8*>(
                    &xb[(long)(iy * Win + ix) * Cin + cc * 32 + qs * 8]);
            *reinterpret_cast<u16x8*>(&XS[pp * 32 + ql * 8]) = v;
        }
        {
            int m = t >> 2, q = t & 3;
            int chq = q ^ ((m >> 1) & 3);
            #pragma unroll
            for (int tap = 0; tap < 4; ++tap) {
                u16x8 v = *reinterpret_cast<const u16x8*>(
                    &wp[((long)((par * 4 + tap) * Cout + o0 + m)) * Cin + cc * 32 + q * 8]);
                *reinterpret_cast<u16x8*>(&WS[tap * 2048 + m * 32 + chq * 8]) = v;
            }
        }
        __syncthreads();

        #pragma unroll
        for (int tap = 0; tap < 4; ++tap) {
            int u = tap >> 1, v = tap & 1;
            bf16x8 af[4], bfr[2];
            #pragma unroll
            for (int mf = 0; mf < 4; ++mf) {
                int row = mf * 16 + l15;
                int ch = kc ^ ((row >> 1) & 3);
                af[mf] = *reinterpret_cast<const bf16x8*>(&WS[tap * 2048 + row * 32 + ch * 8]);
            }
            #pragma unroll
            for (int nf = 0; nf < 2; ++nf) {
                int n = wid * 32 + nf * 16 + l15;
                int rn = n >> cshift, cn = n & (CW - 1);
                int pp = (rn + u) * CW1 + cn + v;
                int ch = kc ^ ((pp >> 1) & 3);
                bfr[nf] = *reinterpret_cast<const bf16x8*>(&XS[pp * 32 + ch * 8]);
            }
            #pragma unroll
            for (int mf = 0; mf < 4; ++mf)
                #pragma unroll
                for (int nf = 0; nf < 2; ++nf)
                    acc[mf][nf] = __builtin_amdgcn_mfma_f32_16x16x32_bf16(
                        af[mf], bfr[nf], acc[mf][nf], 0, 0, 0);
        }
    }

    int kc4 = lane >> 4;
    #pragma unroll
    for (int nf = 0; nf < 2; ++nf) {
        int n = wid * 32 + nf * 16 + l15;
        int rn = n >> cshift, cn = n & (CW - 1);
        int y = 2 * (i0 + rn) + py;
        int xx = 2 * cn + px;
        int pout = y * 2 * Win + xx;
        #pragma unroll
        for (int mf = 0; mf < 4; ++mf) {
            ushort4 hb;
            #pragma unroll
            for (int r = 0; r < 4; ++r) {
                int m = mf * 16 + kc4 * 4 + r;
                int o = o0 + m;
                float s = g[o] * rsqrtf(va[o] + EPSV);
                float v = (acc[mf][nf][r] + bias[o]) * s + (be[o] - mu[o] * s);
                if (res) v += res[((long)(b * Cout) + o) * Pout + pout];
                if (of32) of32[((long)(b * Cout) + o) * Pout + pout] = v;
                ((unsigned short*)&hb)[r] = f2bf(v);
            }
            if (obf)
                *reinterpret_cast<ushort4*>(
                    &obf[(long)(b * Pout + pout) * OCtot + cof + o0 + mf * 16 + kc4 * 4]) = hb;
        }
    }
}

// ---------------- fused lift_net: 1024 thr = 64 px x 16 oc-groups, scalar weights ----------------
__global__ __launch_bounds__(1024) void lift_net_kernel(
    const float* __restrict__ xA, const float* __restrict__ xB,
    const float* __restrict__ oA, const float* __restrict__ oB,
    float* __restrict__ uA, float* __restrict__ uB,
    int x_sB, int x_sC, int x_sR, int x_sA,
    int o_sB, int o_sC, int o_sR, int o_sA,
    int u_sB, int u_sC, int u_sR, int u_sA,
    const float* __restrict__ w1, const float* __restrict__ b1,
    const float* __restrict__ w2, const float* __restrict__ b2,
    int R, int L, int lsh, float sign,
    unsigned short* __restrict__ obf, int Pb, int OCb, int cofA, int cofB)
{
    __shared__ float xsm[4864];
    __shared__ float hsm[8192];
    int t = threadIdx.x;
    int g = t & 63, ocg = t >> 6;
    int b = blockIdx.z;
    int sel = blockIdx.y;
    const float* xin = sel ? xB : xA;
    const float* oth = sel ? oB : oA;
    float* outp = sel ? uB : uA;
    int cofb = sel ? cofB : cofA;
    int rpb = 64 >> lsh;
    int row0 = blockIdx.x * rpb;
    int Lp = L + 3;
    int total = 64 * rpb * Lp;
    for (int idx = t; idx < total; idx += 1024) {
        int c = idx / (rpb * Lp);
        int rem = idx - c * rpb * Lp;
        int rr_l = rem / Lp;
        int q = rem - rr_l * Lp;
        int s = q - 2;
        s = (s < 0) ? -s : s;
        if (s >= L) s = 2 * L - 2 - s;
        xsm[idx] = xin[b * x_sB + c * x_sC + (row0 + rr_l) * x_sR + s * x_sA];
    }
    __syncthreads();

    int ocgu = __builtin_amdgcn_readfirstlane(ocg);
    int rl = g >> lsh, jl = g & (L - 1);
    const float* w1u = w1 + ocgu * 8 * 256;
    float acc1[8] = {};
    for (int c = 0; c < 64; ++c) {
        const float* xr = &xsm[(c * rpb + rl) * Lp + jl];
        float x0 = xr[0], x1 = xr[1], x2 = xr[2], x3 = xr[3];
        const float* wc = w1u + c * 4;
        #pragma unroll
        for (int k = 0; k < 8; ++k) {
            const float* wr = wc + k * 256;
            acc1[k] += wr[0] * x0 + wr[1] * x1 + wr[2] * x2 + wr[3] * x3;
        }
    }
    #pragma unroll
    for (int k = 0; k < 8; ++k) {
        int oc = ocgu * 8 + k;
        hsm[oc * 64 + g] = fmaxf(acc1[k] + b1[oc], 0.f);
    }
    __syncthreads();

    const float* w2u = w2 + ocgu * 4 * 128;
    float acc2[4] = {};
    for (int h4 = 0; h4 < 32; ++h4) {
        float hv0 = hsm[(h4 * 4 + 0) * 64 + g];
        float hv1 = hsm[(h4 * 4 + 1) * 64 + g];
        float hv2 = hsm[(h4 * 4 + 2) * 64 + g];
        float hv3 = hsm[(h4 * 4 + 3) * 64 + g];
        #pragma unroll
        for (int kk = 0; kk < 4; ++kk) {
            const float* wr = w2u + kk * 128 + h4 * 4;
            acc2[kk] += wr[0] * hv0 + wr[1] * hv1 + wr[2] * hv2 + wr[3] * hv3;
        }
    }
    int rg = row0 + rl;
    int p = rg * u_sR + jl * u_sA;
    #pragma unroll
    for (int kk = 0; kk < 4; ++kk) {
        int o = ocgu * 4 + kk;
        float v = oth[b * o_sB + o * o_sC + rg * o_sR + jl * o_sA]
                + sign * tanhf(acc2[kk] + b2[o]);
        outp[b * u_sB + o * u_sC + p] = v;
        if (obf) obf[(long)(b * Pb + p) * OCb + cofb + o] = f2bf(v);
    }
}

// ---------------- fused dw3x3 + relu + dw3x3 + scale + inflate gather + residual ----------------
// grid: 512 blocks = (b*256+c). Whole 64x64 plane pipeline in LDS.
__global__ __launch_bounds__(256) void dw_fused_kernel(
    const float* __restrict__ r2, const float* __restrict__ w1, const float* __restrict__ b1,
    const float* __restrict__ w2, const float* __restrict__ b2v,
    const float* __restrict__ scw, const float* __restrict__ tok,
    const int* __restrict__ idx, float* __restrict__ out)
{
    __shared__ float s0[64][68];
    __shared__ float s1[64][68];
    __shared__ float s2[4096];
    int bc = blockIdx.x;
    int c = bc & 255;
    int t = threadIdx.x;
    const float* xp = r2 + (long)bc * 4096;
    for (int i = t; i < 4096; i += 256) s0[i >> 6][i & 63] = xp[i];
    float wa[9], wb[9];
    #pragma unroll
    for (int k = 0; k < 9; ++k) { wa[k] = w1[c * 9 + k]; wb[k] = w2[c * 9 + k]; }
    float ba = b1[c], bb = b2v[c], sc = scw[c];
    __syncthreads();
    for (int i = t; i < 4096; i += 256) {
        int y = i >> 6, x = i & 63;
        float a = ba;
        #pragma unroll
        for (int ky = 0; ky < 3; ++ky) {
            int yy = y + ky - 1;
            if (yy < 0 || yy > 63) continue;
            #pragma unroll
            for (int kx = 0; kx < 3; ++kx) {
                int xx = x + kx - 1;
                if (xx < 0 || xx > 63) continue;
                a += wa[ky * 3 + kx] * s0[yy][xx];
            }
        }
        s1[y][x] = fmaxf(a, 0.f);
    }
    __syncthreads();
    for (int i = t; i < 4096; i += 256) {
        int y = i >> 6, x = i & 63;
        float a = bb;
        #pragma unroll
        for (int ky = 0; ky < 3; ++ky) {
            int yy = y + ky - 1;
            if (yy < 0 || yy > 63) continue;
            #pragma unroll
            for (int kx = 0; kx < 3; ++kx) {
                int xx = x + kx - 1;
                if (xx < 0 || xx > 63) continue;
                a += wb[ky * 3 + kx] * s1[yy][xx];
            }
        }
        s2[i] = a * sc;
    }
    __syncthreads();
    long base = (long)bc << 13;
    const int4* ip = (const int4*)(idx + base);
    const float4* tp = (const float4*)(tok + base);
    float4* op = (float4*)(out + base);
    for (int i = t; i < 2048; i += 256) {
        int4 iv = ip[i];
        float4 tv = tp[i];
        float4 o;
        o.x = tv.x + s2[iv.x];
        o.y = tv.y + s2[iv.y];
        o.z = tv.z + s2[iv.z];
        o.w = tv.w + s2[iv.w];
        op[i] = o;
    }
}

extern "C" void kernel_launch(void* const* d_in, const int* in_sizes, int n_in,
                              void* d_out, int out_size, void* d_ws, size_t ws_size,
                              hipStream_t stream)
{
    const float* tokens = (const float*)d_in[0];
    const float* fm     = (const float*)d_in[1];
    const int*   infl   = (const int*)d_in[2];
    const float* bng = (const float*)d_in[3];
    const float* bnb = (const float*)d_in[4];
    const float* bnm = (const float*)d_in[5];
    const float* bnv = (const float*)d_in[6];
    const float* red_w = (const float*)d_in[7];
    const float* red_b = (const float*)d_in[8];
    const float* lw1 = (const float*)d_in[9];
    const float* lb1 = (const float*)d_in[10];
    const float* lw2 = (const float*)d_in[11];
    const float* lb2 = (const float*)d_in[12];
    const float* f2w1 = (const float*)d_in[13];
    const float* f2b1 = (const float*)d_in[14];
    const float* f2w2 = (const float*)d_in[15];
    const float* f2b2 = (const float*)d_in[16];
    const float* ct2w = (const float*)d_in[17];
    const float* ct2b = (const float*)d_in[18];
    const float* bn2g = (const float*)d_in[19];
    const float* bn2b = (const float*)d_in[20];
    const float* bn2m = (const float*)d_in[21];
    const float* bn2v = (const float*)d_in[22];
    const float* f1w1 = (const float*)d_in[23];
    const float* f1b1 = (const float*)d_in[24];
    const float* f1w2 = (const float*)d_in[25];
    const float* f1b2 = (const float*)d_in[26];
    const float* ct1w = (const float*)d_in[27];
    const float* ct1b = (const float*)d_in[28];
    const float* bn1g = (const float*)d_in[29];
    const float* bn1b = (const float*)d_in[30];
    const float* bn1m = (const float*)d_in[31];
    const float* bn1v = (const float*)d_in[32];
    const float* dw1w = (const float*)d_in[33];
    const float* dw1b = (const float*)d_in[34];
    const float* dw2w = (const float*)d_in[35];
    const float* dw2b = (const float*)d_in[36];
    const float* scw  = (const float*)d_in[37];

    float* ws = (float*)d_ws;
    unsigned short* Abf = (unsigned short*)ws;                    // 2,097,152 fl
    float* part  = ws + 2097152;                                  // 4 x 2,097,152 fl
    float* rgrid = ws + 18874368;                                 // 2,097,152
    unsigned short* rgrid_bf = (unsigned short*)(ws + 20971520);  // 1,048,576 fl
    float* rr    = ws + 22020096;   // 524,288
    float* c1    = ws + 22544384;   // 262,144
    float* d1    = ws + 22806528;   // 262,144
    float* c2    = ws + 23068672;   // 65,536
    float* d2    = ws + 23134208;   // 65,536
    float* x2    = ws + 23199744;   // 131,072
    unsigned short* x2_bf  = (unsigned short*)(ws + 23330816);    // 65,536 fl
    float* x1    = ws + 23396352;   // 786,432
    unsigned short* x1_bf  = (unsigned short*)(ws + 24182784);    // 393,216 fl
    unsigned short* g2_bf  = (unsigned short*)(ws + 24576000);    // 65,536 fl
    unsigned short* y2p_bf = (unsigned short*)(ws + 24641536);    // 65,536 fl
    unsigned short* g1_bf  = (unsigned short*)(ws + 24707072);    // 262,144 fl
    unsigned short* y1p_bf = (unsigned short*)(ws + 24969216);    // 262,144 fl
    unsigned short* wp2    = (unsigned short*)(ws + 25231360);    // 262,144 fl
    unsigned short* wp1    = (unsigned short*)(ws + 25493504);    // 524,288 fl
    float* r2 = ws + 26017792;      // 2,097,152

    // weight packs (independent)
    wpack_kernel<<<512, 256, 0, stream>>>(ct1w, wp1, 256, 256);
    wpack_kernel<<<256, 256, 0, stream>>>(ct2w, wp2, 128, 256);

    // 1. BN -> bf16
    bn_to_bf16_kernel<<<4096, 256, 0, stream>>>((const float4*)tokens, (ushort4*)Abf,
                                                bng, bnb, bnm, bnv);
    // 2. flatten einsum (MFMA pipelined, K-split 4) + reduce/transpose
    flatten_gemm_mfma<<<dim3(64, 1, 8), 256, 0, stream>>>(Abf, fm, part);
    add4_t_kernel<<<dim3(64, 4, 2), 256, 0, stream>>>(part, rgrid, rgrid_bf);
    // 3. reduce 1x1 (256->64), f32 out
    conv1x1_mfma<2><<<dim3(32, 1, 2), 256, 0, stream>>>(rgrid_bf, red_w, red_b,
                                                        rr, (unsigned short*)nullptr,
                                                        256, 64, 4096, 0);

    auto lift2 = [&](const float* xA, const float* xB, const float* oA, const float* oB,
                     float* uA, float* uB,
                     int xsB, int xsC, int xsR, int xsA,
                     int osB, int osC, int osR, int osA,
                     int usB, int usC, int usR, int usA,
                     int lvl, int sch, int net, int R, int L, float sign,
                     unsigned short* obf, int Pb, int OCb, int cofA, int cofB, int nsel) {
        int widx = (lvl * 2 + sch) * 2 + net;
        int lsh = (L == 32) ? 5 : 4;
        lift_net_kernel<<<dim3(R * L / 64, nsel, 2), 1024, 0, stream>>>(
            xA, xB, oA, oB, uA, uB,
            xsB, xsC, xsR, xsA, osB, osC, osR, osA, usB, usC, usR, usA,
            lw1 + widx * 32768, lb1 + widx * 128, lw2 + widx * 8192, lb2 + widx * 64,
            R, L, lsh, sign, obf, Pb, OCb, cofA, cofB);
    };

    // ---- stage 1: L1 horizontal P -> d1 ----
    lift2(rr, rr, rr + 1, rr + 1, d1, d1,
          262144, 4096, 64, 2,  262144, 4096, 64, 2,  131072, 2048, 32, 1,
          0, 0, 0, 64, 32, -1.f, nullptr, 0, 0, 0, 0, 1);
    // ---- stage 2: L1 horizontal U -> c1 ----
    lift2(d1, d1, rr, rr, c1, c1,
          131072, 2048, 32, 1,  262144, 4096, 64, 2,  131072, 2048, 32, 1,
          0, 0, 1, 64, 32, +1.f, nullptr, 0, 0, 0, 0, 1);
    // ---- stage 3: L1 vertical P pair ----
    lift2(c1, d1, c1 + 32, d1 + 32, x1 + 65536, x1 + 196608,
          131072, 2048, 1, 64,  131072, 2048, 1, 64,  393216, 1024, 1, 32,
          0, 1, 0, 32, 32, -1.f, x1_bf, 1024, 384, 64, 192, 2);
    // ---- stage 4: L1 vertical U pair ----
    lift2(x1 + 65536, x1 + 196608, c1, d1, x1, x1 + 131072,
          393216, 1024, 1, 32,  131072, 2048, 1, 64,  393216, 1024, 1, 32,
          0, 1, 1, 32, 32, +1.f, x1_bf, 1024, 384, 0, 128, 2);
    // ---- stage 5: L2 horizontal P on LL1 -> d2 ----
    lift2(x1, x1, x1 + 1, x1 + 1, d2, d2,
          393216, 1024, 32, 2,  393216, 1024, 32, 2,  65536, 512, 16, 1,
          1, 0, 0, 32, 16, -1.f, nullptr, 0, 0, 0, 0, 1);
    // ---- stage 6: L2 horizontal U -> c2 ----
    lift2(d2, d2, x1, x1, c2, c2,
          65536, 512, 16, 1,  393216, 1024, 32, 2,  65536, 512, 16, 1,
          1, 0, 1, 32, 16, +1.f, nullptr, 0, 0, 0, 0, 1);
    // ---- stage 7: L2 vertical P pair ----
    lift2(c2, d2, c2 + 16, d2 + 16, x2 + 16384, x2 + 49152,
          65536, 512, 1, 32,  65536, 512, 1, 32,  65536, 256, 1, 16,
          1, 1, 0, 16, 16, -1.f, x2_bf, 256, 256, 64, 192, 2);
    // ---- stage 8: L2 vertical U pair ----
    lift2(x2 + 16384, x2 + 49152, c2, d2, x2, x2 + 32768,
          65536, 256, 1, 16,  65536, 512, 1, 32,  65536, 256, 1, 16,
          1, 1, 1, 16, 16, +1.f, x2_bf, 256, 256, 0, 128, 2);

    // ---- ff2 (bf16 chain) + ct2 -> x1_bf ch 256..383 ----
    conv1x1_mfma<1><<<dim3(4, 4, 2), 256, 0, stream>>>(x2_bf, f2w1, f2b1,
        (float*)nullptr, g2_bf, 256, 256, 256, 2);
    conv1x1_mfma<1><<<dim3(4, 4, 2), 256, 0, stream>>>(g2_bf, f2w2, f2b2,
        (float*)nullptr, y2p_bf, 256, 256, 256, 0);
    convt_mfma<<<dim3(2, 2, 8), 256, 0, stream>>>(y2p_bf, wp2, ct2b,
        bn2g, bn2b, bn2m, bn2v, (const float*)nullptr,
        (float*)nullptr, x1_bf, 256, 128, 16, 16, 8, 4, 384, 256);

    // ---- ff1 + ct1 (+res rgrid) -> r2 f32 ----
    conv1x1_mfma<2><<<dim3(8, 4, 2), 256, 0, stream>>>(x1_bf, f1w1, f1b1,
        (float*)nullptr, g1_bf, 384, 256, 1024, 2);
    conv1x1_mfma<2><<<dim3(8, 4, 2), 256, 0, stream>>>(g1_bf, f1w2, f1b2,
        (float*)nullptr, y1p_bf, 256, 256, 1024, 0);
    convt_mfma<<<dim3(8, 4, 8), 256, 0, stream>>>(y1p_bf, wp1, ct1b,
        bn1g, bn1b, bn1m, bn1v, rgrid,
        r2, (unsigned short*)nullptr, 256, 256, 32, 32, 4, 5, 0, 0);

    // ---- fused depthwise x2 + scale + gather + residual ----
    dw_fused_kernel<<<512, 256, 0, stream>>>(r2, dw1w, dw1b, dw2w, dw2b, scw,
                                             tokens, infl, (float*)d_out);
}